// Round 7
// baseline (543.302 us; speedup 1.0000x reference)
//
#include <hip/hip_runtime.h>
#include <hip/hip_cooperative_groups.h>
#include <cstdint>
#include <cstddef>

namespace cg = cooperative_groups;

// ============================================================================
// MaskGenerator R11: cooperative mega-kernel, hardened vs R10's failure.
//  - R10 launched EXACTLY 512 blocks (= theoretical 2/CU capacity); if the
//    driver reserves anything, grid.sync() deadlocks -> GPU hang. R11 queries
//    hipOccupancyMaxActiveBlocksPerMultiprocessor (host-side, capture-safe,
//    cached) and launches min(512, perCU*256).
//  - ALL phases are grid-stride loops -> correct for any grid size >= 1.
//  - Phase bodies byte-identical to validated R9/R10 numerics:
//    phase1 MLP rows -> h3b, scl, wp, shv;  phase2 GEMM 512 tiles -> mn;
//    phase3 noise over mn high halves;      phase4 faug 1024 tiles -> final.
// ============================================================================

typedef unsigned int u32;
typedef unsigned short u16;

#define Bd 256
#define Ld 512
#define Fd 64
#define Nd 32768            // Ld*Fd

struct U2 { u32 a, b; };

__device__ __forceinline__ u32 rotl32(u32 x, int r){ return (x << r) | (x >> (32 - r)); }

__device__ __forceinline__ U2 tf2x32(u32 k0, u32 k1, u32 x0, u32 x1){
  u32 ks2 = k0 ^ k1 ^ 0x1BD11BDAu;
  x0 += k0; x1 += k1;
#define TFR4(r0,r1,r2,r3) \
  x0 += x1; x1 = rotl32(x1, r0); x1 ^= x0; \
  x0 += x1; x1 = rotl32(x1, r1); x1 ^= x0; \
  x0 += x1; x1 = rotl32(x1, r2); x1 ^= x0; \
  x0 += x1; x1 = rotl32(x1, r3); x1 ^= x0;
  TFR4(13,15,26,6)  x0 += k1;  x1 += ks2 + 1u;
  TFR4(17,29,16,24) x0 += ks2; x1 += k0 + 2u;
  TFR4(13,15,26,6)  x0 += k0;  x1 += k1 + 3u;
  TFR4(17,29,16,24) x0 += k1;  x1 += ks2 + 4u;
  TFR4(13,15,26,6)  x0 += ks2; x1 += k0 + 5u;
#undef TFR4
  U2 r; r.a = x0; r.b = x1; return r;
}

__device__ __forceinline__ u32 rb32(u32 k0, u32 k1, u32 i){
  U2 r = tf2x32(k0, k1, 0u, i);
  return r.a ^ r.b;
}

__device__ __forceinline__ U2 split_key(u32 k0, u32 k1, u32 j){
  return tf2x32(k0, k1, 0u, j);
}

__device__ __forceinline__ float sigmoidf_(float x){ return 1.0f / (1.0f + expf(-x)); }
__device__ __forceinline__ float softplusf_(float x){ return fmaxf(x, 0.0f) + log1pf(expf(-fabsf(x))); }
__device__ __forceinline__ float leakyf_(float x){ return (x > 0.0f) ? x : 0.2f * x; }

__device__ __forceinline__ float erfinvf_(float x){
  float w = -log1pf(-x * x);
  float p;
  if (w < 5.0f){
    w -= 2.5f;
    p =               2.81022636e-08f;
    p = fmaf(p, w,    3.43273939e-07f);
    p = fmaf(p, w,   -3.5233877e-06f);
    p = fmaf(p, w,   -4.39150654e-06f);
    p = fmaf(p, w,    0.00021858087f);
    p = fmaf(p, w,   -0.00125372503f);
    p = fmaf(p, w,   -0.00417768164f);
    p = fmaf(p, w,    0.246640727f);
    p = fmaf(p, w,    1.50140941f);
  } else {
    w = sqrtf(w) - 3.0f;
    p =              -0.000200214257f;
    p = fmaf(p, w,    0.000100950558f);
    p = fmaf(p, w,    0.00134934322f);
    p = fmaf(p, w,   -0.00367342844f);
    p = fmaf(p, w,    0.00573950773f);
    p = fmaf(p, w,   -0.0076224613f);
    p = fmaf(p, w,    0.00943887047f);
    p = fmaf(p, w,    1.00167406f);
    p = fmaf(p, w,    2.83297682f);
  }
  return p * x;
}

__device__ __forceinline__ float uniform_from_bits(u32 bits){
  return __uint_as_float((bits >> 9) | 0x3f800000u) - 1.0f;
}

__device__ __forceinline__ float normal_from_bits(u32 bits){
  float u01 = uniform_from_bits(bits);
  const float lo = -0.99999994f;
  float v = fmaf(u01, 2.0f, lo);
  v = fmaxf(lo, v);
  return 1.41421356f * erfinvf_(v);
}

__device__ __forceinline__ int warp_idx_(int t, int wp, int sh){
  int tps = t + sh;
  int pos = (t >= wp) ? ((tps < Ld - 1) ? tps : (Ld - 1)) : t;
  int neg = ((t >= wp + sh) && (t < Ld + sh)) ? (t - sh) : t;
  return (sh > 0) ? pos : ((sh < 0) ? neg : t);
}

__device__ __forceinline__ u32 pack_bf16_2(float a, float b){
  u32 ua = __float_as_uint(a), ub = __float_as_uint(b);
  u32 ra = (ua + 0x7FFFu + ((ua >> 16) & 1u)) >> 16;
  u32 rb = (ub + 0x7FFFu + ((ub >> 16) & 1u)) >> 16;
  return (ra & 0xFFFFu) | (rb << 16);
}
__device__ __forceinline__ u16 f2bf(float a){
  u32 ua = __float_as_uint(a);
  return (u16)((ua + 0x7FFFu + ((ua >> 16) & 1u)) >> 16);
}
__device__ __forceinline__ float bf2f(u16 v){
  return __uint_as_float(((u32)v) << 16);
}

__device__ __forceinline__ int swz_(int v){
  return ((v >> 2) & 7) ^ ((v & 3) << 1);
}
__device__ __forceinline__ int rev9_(int k){
  return (int)(__brev((u32)k) >> 23);
}

typedef short short8 __attribute__((ext_vector_type(8)));
typedef float f32x4 __attribute__((ext_vector_type(4)));
union Frag { uint4 u; short8 s; };

#define PITCH 529
__device__ __forceinline__ int lphys(int t){ return t + (t >> 5); }

// ---------------------------------------------------------------------------
__global__ __launch_bounds__(256, 2) void k_mega(
    const float* __restrict__ x,
    const float* __restrict__ w1, const float* __restrict__ b1,
    const float* __restrict__ w2, const float* __restrict__ b2,
    const float* __restrict__ w3, const float* __restrict__ b3,
    const float* __restrict__ wm, const float* __restrict__ bm,
    const float* __restrict__ wn, const float* __restrict__ bn,
    const float* __restrict__ wsc, const float* __restrict__ bsc,
    const float* __restrict__ pm, const float* __restrict__ pn,
    const float* __restrict__ psh, const float* __restrict__ psc,
    u16* __restrict__ h3b, float* __restrict__ scl,
    int* __restrict__ wp, int* __restrict__ shv,
    u32* mn)
{
  cg::grid_group grid = cg::this_grid();
  __shared__ __align__(16) u32 SMEM[12288];      // 48 KB, phase-unioned

  const int bid = blockIdx.x;
  const int tid = threadIdx.x;
  const int gsz = gridDim.x;

  // ======================= phase 1: MLP (grid-stride over 256 rows) ========
  for (int b = bid; b < 256; b += gsz){
    float* zs  = (float*)SMEM;       // 64
    float* h1s = zs + 64;            // 128
    float* h2s = h1s + 128;          // 256
    float* hs  = h2s + 256;          // 256
    int n = tid;
    __syncthreads();                 // guard LDS reuse across strided rows

    if (n < 64){
      U2 kz = split_key(0u, 42u, 0u);
      zs[n] = normal_from_bits(rb32(kz.a, kz.b, (u32)(b * 64 + n)));
    }
    __syncthreads();

    if (n < 128){
      float acc = b1[n];
      #pragma unroll 8
      for (int k = 0; k < 64; ++k) acc = fmaf(zs[k], w1[k * 128 + n], acc);
      h1s[n] = leakyf_(acc);
    }
    __syncthreads();

    {
      float acc = b2[n];
      #pragma unroll 8
      for (int k = 0; k < 128; ++k) acc = fmaf(h1s[k], w2[k * 256 + n], acc);
      h2s[n] = leakyf_(acc);
    }
    __syncthreads();

    {
      float acc = b3[n];
      #pragma unroll 8
      for (int k = 0; k < 256; ++k) acc = fmaf(h2s[k], w3[k * 256 + n], acc);
      u16 hv = f2bf(leakyf_(acc));
      h3b[b * 256 + n] = hv;
      hs[n] = bf2f(hv);
    }
    __syncthreads();

    if (n < 64){
      float a2 = bsc[n];
      for (int k = 0; k < 256; ++k) a2 = fmaf(hs[k], wsc[k * 64 + n], a2);
      float s_scale = sigmoidf_(psc[0]);
      scl[b * 64 + n] = 1.0f + (softplusf_(a2) - 0.5f) * 0.2f * s_scale;
    }

    if (b < 2 && n < 128){
      int bb = b * 128 + n;
      float s_shift = sigmoidf_(psh[0]);
      int wsteps = (int)(51.2f * s_shift);
      U2 kwp = split_key(0u, 42u, 2u);
      U2 ksh = split_key(0u, 42u, 3u);
      {
        U2 k1 = split_key(kwp.a, kwp.b, 0u);
        U2 k2 = split_key(kwp.a, kwp.b, 1u);
        u32 hi = rb32(k1.a, k1.b, (u32)bb);
        u32 lo = rb32(k2.a, k2.b, (u32)bb);
        u32 span = (u32)(Ld - 2 * wsteps);
        u32 mult = 65536u % span; mult = (mult * mult) % span;
        u32 off = ((hi % span) * mult + (lo % span)) % span;
        wp[bb] = wsteps + (int)off;
      }
      {
        U2 k1 = split_key(ksh.a, ksh.b, 0u);
        U2 k2 = split_key(ksh.a, ksh.b, 1u);
        u32 hi = rb32(k1.a, k1.b, (u32)bb);
        u32 lo = rb32(k2.a, k2.b, (u32)bb);
        u32 span = (u32)(2 * wsteps + 1);
        u32 mult = 65536u % span; mult = (mult * mult) % span;
        u32 off = ((hi % span) * mult + (lo % span)) % span;
        shv[bb] = -wsteps + (int)off;
      }
    }
  }
  grid.sync();

  // ======================= phase 2: GEMM (grid-stride over 512 tiles) ======
  {
    u32* As  = SMEM;              // 16 KB
    u32* Bs0 = SMEM + 4096;       // 16 KB
    u32* Bs1 = SMEM + 8192;       // 16 KB

    const int lane = tid & 63;
    const int w    = tid >> 6;
    const int q    = lane >> 4;
    const int lo   = lane & 15;
    const int wr   = (w >> 1) << 6;
    const int wc   = (w & 1) << 6;

    const int p  = lane >> 3;
    const int c8 = lane & 7;
    const int nb = (w << 5) + (p << 2);

    for (int tile = bid; tile < 512; tile += gsz){
      const int nt0 = (tile & 255) << 7;
      const int b0  = (tile >> 8) << 7;

      f32x4 accm[4][4], accn[4][4];
      #pragma unroll
      for (int i = 0; i < 4; ++i)
        #pragma unroll
        for (int j = 0; j < 4; ++j){ accm[i][j] = (f32x4)0.0f; accn[i][j] = (f32x4)0.0f; }

      for (int kc = 0; kc < 256; kc += 64){
        __syncthreads();
        #pragma unroll
        for (int j = 0; j < 4; ++j){
          int idx  = j * 256 + tid;
          int row  = idx >> 3;
          int slot = idx & 7;
          int g    = slot ^ swz_(row);
          uint4 v  = *(const uint4*)(h3b + (size_t)(b0 + row) * 256 + kc + g * 8);
          *(uint4*)&As[row * 32 + slot * 4] = v;
        }
        #pragma unroll
        for (int cp = 0; cp < 4; ++cp){
          int c = cp * 8 + c8;
          size_t gb = (size_t)(kc + 2 * c) * Nd + nt0 + nb;
          float4 m0 = *(const float4*)(wm + gb);
          float4 m1 = *(const float4*)(wm + gb + Nd);
          float4 v0 = *(const float4*)(wn + gb);
          float4 v1 = *(const float4*)(wn + gb + Nd);
          int g = c >> 2, cl = c & 3;
          #pragma unroll
          for (int s = 0; s < 4; ++s){
            int n = nb + s;
            int addr = n * 32 + (g ^ swz_(n)) * 4 + cl;
            float a0 = (s == 0) ? m0.x : (s == 1) ? m0.y : (s == 2) ? m0.z : m0.w;
            float a1 = (s == 0) ? m1.x : (s == 1) ? m1.y : (s == 2) ? m1.z : m1.w;
            float b0f = (s == 0) ? v0.x : (s == 1) ? v0.y : (s == 2) ? v0.z : v0.w;
            float b1f = (s == 0) ? v1.x : (s == 1) ? v1.y : (s == 2) ? v1.z : v1.w;
            Bs0[addr] = pack_bf16_2(a0, a1);
            Bs1[addr] = pack_bf16_2(b0f, b1f);
          }
        }
        __syncthreads();

        #pragma unroll
        for (int u = 0; u < 2; ++u){
          int G = u * 4 + q;
          Frag af[4], bfm[4], bfn[4];
          #pragma unroll
          for (int mt = 0; mt < 4; ++mt){
            int row = wr + mt * 16 + lo;
            af[mt].u = *(const uint4*)&As[row * 32 + (G ^ swz_(row)) * 4];
          }
          #pragma unroll
          for (int nt = 0; nt < 4; ++nt){
            int n = wc + nt * 16 + lo;
            int ad = n * 32 + (G ^ swz_(n)) * 4;
            bfm[nt].u = *(const uint4*)&Bs0[ad];
            bfn[nt].u = *(const uint4*)&Bs1[ad];
          }
          #pragma unroll
          for (int mt = 0; mt < 4; ++mt){
            #pragma unroll
            for (int nt = 0; nt < 4; ++nt){
              accm[mt][nt] = __builtin_amdgcn_mfma_f32_16x16x32_bf16(af[mt].s, bfm[nt].s, accm[mt][nt], 0, 0, 0);
              accn[mt][nt] = __builtin_amdgcn_mfma_f32_16x16x32_bf16(af[mt].s, bfn[nt].s, accn[mt][nt], 0, 0, 0);
            }
          }
        }
      }

      #pragma unroll
      for (int nt = 0; nt < 4; ++nt){
        int n = nt0 + wc + nt * 16 + lo;
        float bmv = bm[n];
        float bnv = bn[n];
        #pragma unroll
        for (int mt = 0; mt < 4; ++mt){
          #pragma unroll
          for (int r = 0; r < 4; ++r){
            int b = b0 + wr + mt * 16 + q * 4 + r;
            size_t o = (size_t)b * Nd + n;
            mn[o] = pack_bf16_2(accm[mt][nt][r] + bmv, accn[mt][nt][r] + bnv);
          }
        }
      }
    }
  }
  grid.sync();

  // ======================= phase 3: noise (grid-stride) ====================
  {
    float s_noise = sigmoidf_(pn[0]);
    float sc = s_noise * 0.05f;
    U2 knk = split_key(0u, 42u, 1u);
    for (int nb2 = bid; nb2 < 4096; nb2 += gsz){
      int gid = nb2 * 256 + tid;
      u32 base = (u32)gid * 8u;
      uint4 v0 = *(const uint4*)(mn + base);
      uint4 v1 = *(const uint4*)(mn + base + 4);
      u32 wds[8] = {v0.x, v0.y, v0.z, v0.w, v1.x, v1.y, v1.z, v1.w};
      #pragma unroll
      for (int h = 0; h < 8; ++h){
        u16 logit = (u16)(wds[h] >> 16);
        float nm = softplusf_(bf2f(logit));
        float nz = normal_from_bits(rb32(knk.a, knk.b, base + (u32)h));
        wds[h] = (wds[h] & 0xFFFFu) | ((u32)f2bf(nz * nm * sc) << 16);
      }
      *(uint4*)(mn + base)     = make_uint4(wds[0], wds[1], wds[2], wds[3]);
      *(uint4*)(mn + base + 4) = make_uint4(wds[4], wds[5], wds[6], wds[7]);
    }
  }
  grid.sync();

  // ======================= phase 4: faug (grid-stride over 1024 tiles) =====
  {
    float*  SR = (float*)SMEM;              // 4232 floats
    float*  SI = SR + 8 * PITCH;            // 4232 floats
    float2* tw = (float2*)(SI + 8 * PITCH); // 256 float2

    float s_mask  = sigmoidf_(pm[0]);
    float s_shift = sigmoidf_(psh[0]);
    float s_mix   = 1.0f - s_shift;
    float ratio   = fminf(s_mix * 0.1f, 0.5f);
    float wa = 1.0f - s_mix - s_shift;
    wa = fminf(fmaxf(wa, 0.1f), 0.8f);
    float wb = s_mix * 0.5f;
    float wc = s_shift * 0.5f;
    float tot = wa + wb + wc;
    wa /= tot; wb /= tot; wc /= tot;
    bool pass = (s_mix < 0.01f);

    U2 kf = split_key(0u, 42u, 4u);

    {
      float ang = -6.283185307179586f * ((float)tid / 512.0f);
      tw[tid] = make_float2(cosf(ang), sinf(ang));
    }

    for (int tile = bid; tile < 1024; tile += gsz){
      const int b  = tile >> 2;
      const int f0 = (tile & 3) << 4;
      const int wpb = wp[b];
      const int shb = shv[b];
      __syncthreads();      // protect SR/SI (and tw on first iter) before reuse

      // ---- stage in + pack pairs ----
      const float* xb = x + (size_t)b * Nd;
      #pragma unroll
      for (int s = 0; s < 8; ++s){
        int qq = (s << 8) + tid;
        int t  = qq >> 2;
        int f4 = qq & 3;
        float4 v = *(const float4*)(xb + t * 64 + f0 + (f4 << 2));
        int j = f4 << 1;
        int pt = lphys(t);
        SR[j * PITCH + pt]       = v.x;  SI[j * PITCH + pt]       = v.y;
        SR[(j + 1) * PITCH + pt] = v.z;  SI[(j + 1) * PITCH + pt] = v.w;
      }
      __syncthreads();

      // ---- forward DIF ----
      for (int s = 9; s >= 1; --s){
        int half = 1 << (s - 1);
        #pragma unroll
        for (int it = 0; it < 8; ++it){
          int j  = it;
          int bi = tid;
          int pos = bi & (half - 1);
          int g = bi >> (s - 1);
          int i1 = (g << s) + pos;
          int i2 = i1 + half;
          int a1 = j * PITCH + lphys(i1);
          int a2 = j * PITCH + lphys(i2);
          float ur = SR[a1], ui = SI[a1];
          float vr = SR[a2], vi = SI[a2];
          SR[a1] = ur + vr; SI[a1] = ui + vi;
          float dr = ur - vr, di = ui - vi;
          float2 w = tw[pos << (9 - s)];
          SR[a2] = dr * w.x - di * w.y;
          SI[a2] = dr * w.y + di * w.x;
        }
        __syncthreads();
      }

      // ---- masked Hermitian repack ----
      #pragma unroll
      for (int it = 0; it < 8; ++it){
        int j = it;
        int k = tid;
        int nItr = (k == 0) ? 2 : 1;
        for (int e = 0; e < nItr; ++e){
          int kk = (e == 0) ? k : 256;
          int nk = (512 - kk) & 511;
          int pk = rev9_(kk), pnn = rev9_(nk);
          int ak = j * PITCH + lphys(pk);
          int an = j * PITCH + lphys(pnn);
          float zkr = SR[ak], zki = SI[ak];
          float znr = SR[an], zni = SI[an];
          float X0r = 0.5f * (zkr + znr), X0i = 0.5f * (zki - zni);
          float X1r = 0.5f * (zki + zni), X1i = 0.5f * (znr - zkr);
          int fA = f0 + (j << 1);
          u32 ck = (u32)((b * Ld + kk) * Fd + fA);
          u32 cn = (u32)((b * Ld + nk) * Fd + fA);
          float k0a = (uniform_from_bits(rb32(kf.a, kf.b, ck))      > ratio) ? 1.0f : 0.0f;
          float k0b = (uniform_from_bits(rb32(kf.a, kf.b, cn))      > ratio) ? 1.0f : 0.0f;
          float k1a = (uniform_from_bits(rb32(kf.a, kf.b, ck + 1u)) > ratio) ? 1.0f : 0.0f;
          float k1b = (uniform_from_bits(rb32(kf.a, kf.b, cn + 1u)) > ratio) ? 1.0f : 0.0f;
          float m0 = 0.5f * (k0a + k0b);
          float m1 = 0.5f * (k1a + k1b);
          SR[ak] = m0 * X0r - m1 * X1i;
          SI[ak] = m0 * X0i + m1 * X1r;
          SR[an] = m0 * X0r + m1 * X1i;
          SI[an] = m1 * X1r - m0 * X0i;
        }
      }
      __syncthreads();

      // ---- inverse DIT ----
      for (int s = 1; s <= 9; ++s){
        int half = 1 << (s - 1);
        #pragma unroll
        for (int it = 0; it < 8; ++it){
          int j  = it;
          int bi = tid;
          int pos = bi & (half - 1);
          int g = bi >> (s - 1);
          int i1 = (g << s) + pos;
          int i2 = i1 + half;
          int a1 = j * PITCH + lphys(i1);
          int a2 = j * PITCH + lphys(i2);
          float2 w = tw[pos << (9 - s)];
          float vr = SR[a2], vi = SI[a2];
          float tx_ = vr * w.x + vi * w.y;
          float ty_ = vi * w.x - vr * w.y;
          float ur = SR[a1], ui = SI[a1];
          SR[a1] = ur + tx_; SI[a1] = ui + ty_;
          SR[a2] = ur - tx_; SI[a2] = ui - ty_;
        }
        __syncthreads();
      }

      // ---- fused augmentation epilogue ----
      const float inv512 = 1.0f / 512.0f;
      u32* mnb = mn + (size_t)b * Nd;
      #pragma unroll
      for (int s = 0; s < 8; ++s){
        int qq = (s << 8) + tid;
        int t  = qq >> 2;
        int f4 = qq & 3;
        int f  = f0 + (f4 << 2);
        int j  = f4 << 1;
        int pt = lphys(t);
        int nidx = t * 64 + f;
        float4 xv = *(const float4*)(xb + nidx);
        int wi = warp_idx_(t, wpb, shb);
        float4 wv = *(const float4*)(xb + wi * 64 + f);
        float4 sc = *(const float4*)(scl + b * 64 + f);
        uint4 w4 = *(const uint4*)(mnb + nidx);
        float fr[4];
        fr[0] = SR[j * PITCH + pt] * inv512;
        fr[1] = SI[j * PITCH + pt] * inv512;
        fr[2] = SR[(j + 1) * PITCH + pt] * inv512;
        fr[3] = SI[(j + 1) * PITCH + pt] * inv512;
        const float xvv[4] = {xv.x, xv.y, xv.z, xv.w};
        const float wvv[4] = {wv.x, wv.y, wv.z, wv.w};
        const float scv[4] = {sc.x, sc.y, sc.z, sc.w};
        const u32 wdv[4] = {w4.x, w4.y, w4.z, w4.w};
        float o[4];
        #pragma unroll
        for (int c = 0; c < 4; ++c){
          float maskv = sigmoidf_(bf2f((u16)(wdv[c] & 0xFFFFu)));
          maskv = 1.0f - (1.0f - maskv) * s_mask * 0.3f;
          float noise = bf2f((u16)(wdv[c] >> 16));
          float fq = pass ? xvv[c] : fr[c];
          float aug = fmaf(xvv[c] * maskv, scv[c], noise);
          o[c] = aug * wa + fq * wb + wvv[c] * wc;
        }
        *(float4*)(mnb + nidx) = make_float4(o[0], o[1], o[2], o[3]);
      }
    }
  }
}

// ---------------------------------------------------------------------------
extern "C" void kernel_launch(void* const* d_in, const int* in_sizes, int n_in,
                              void* d_out, int out_size, void* d_ws, size_t ws_size,
                              hipStream_t stream)
{
  (void)in_sizes; (void)n_in; (void)out_size; (void)ws_size;
  const float* x   = (const float*)d_in[0];
  const float* w1  = (const float*)d_in[2];
  const float* b1  = (const float*)d_in[3];
  const float* w2  = (const float*)d_in[4];
  const float* b2  = (const float*)d_in[5];
  const float* w3  = (const float*)d_in[6];
  const float* b3  = (const float*)d_in[7];
  const float* wm  = (const float*)d_in[8];
  const float* bm  = (const float*)d_in[9];
  const float* wn  = (const float*)d_in[10];
  const float* bn  = (const float*)d_in[11];
  const float* wsc = (const float*)d_in[12];
  const float* bsc = (const float*)d_in[13];
  const float* pm  = (const float*)d_in[14];
  const float* pn  = (const float*)d_in[15];
  const float* psh = (const float*)d_in[16];
  const float* psc = (const float*)d_in[17];
  char* ws = (char*)d_ws;

  int*   wp   = (int*)(ws + 0);
  int*   shv  = (int*)(ws + 1024);
  u16*   h3b  = (u16*)(ws + 4096);
  float* scl  = (float*)(ws + 4096 + 131072);
  u32*   mn   = (u32*)d_out;

  // Occupancy-clamped cooperative grid (host-side query, cached; no stream
  // ops -> graph-capture safe). Grid-stride phases are correct for any size.
  static int coopGrid = 0;
  if (coopGrid == 0){
    int perCU = 0;
    hipError_t e = hipOccupancyMaxActiveBlocksPerMultiprocessor(
        &perCU, (const void*)k_mega, 256, 0);
    if (e != hipSuccess || perCU < 1) perCU = 1;
    long total = (long)perCU * 256;          // 256 CUs on MI355X
    if (total > 512) total = 512;
    if (total < 1)   total = 1;
    coopGrid = (int)total;
  }

  void* args[] = {
    (void*)&x,  (void*)&w1, (void*)&b1, (void*)&w2, (void*)&b2,
    (void*)&w3, (void*)&b3, (void*)&wm, (void*)&bm, (void*)&wn,
    (void*)&bn, (void*)&wsc,(void*)&bsc,(void*)&pm, (void*)&pn,
    (void*)&psh,(void*)&psc,(void*)&h3b,(void*)&scl,(void*)&wp,
    (void*)&shv,(void*)&mn
  };
  hipLaunchCooperativeKernel((const void*)k_mega, dim3(coopGrid), dim3(256),
                             args, 0, stream);
}

// Round 8
// 334.170 us; speedup vs baseline: 1.6258x; 1.6258x over previous
//
#include <hip/hip_runtime.h>
#include <cstdint>
#include <cstddef>

// ============================================================================
// MaskGenerator R12: revert to validated R9 4-kernel chain (315us); mega-
// kernel proven an anti-lever (R11: phase-unioned regalloc + 2 blocks/CU ->
// 385us vs 148us sum; fixed ~160us harness overhead is launch-count-invariant).
// k_faug attacked on two axes, numerics bit-identical:
//  1) freq-mask threefry draws hoisted into k_mlp (grid 8192; blocks 0..255
//     also run the MLP row). m0,m1 in {0,.5,1} stored as a byte per
//     (b, feat-pair, kk) in ws (2.1MB); decoded 0.5f*(float)q -> exact.
//  2) k_faug tile halved: 4 complex series/block, 2048 blocks, LDS ~19KB ->
//     8 blocks/CU (was 4), same counters/math per element.
// k_gemm / k_noise byte-identical to validated R9. mn packed in d_out (R9).
// ============================================================================

typedef unsigned int u32;
typedef unsigned short u16;
typedef unsigned char u8;

#define Bd 256
#define Ld 512
#define Fd 64
#define Nd 32768            // Ld*Fd

struct U2 { u32 a, b; };

__device__ __forceinline__ u32 rotl32(u32 x, int r){ return (x << r) | (x >> (32 - r)); }

__device__ __forceinline__ U2 tf2x32(u32 k0, u32 k1, u32 x0, u32 x1){
  u32 ks2 = k0 ^ k1 ^ 0x1BD11BDAu;
  x0 += k0; x1 += k1;
#define TFR4(r0,r1,r2,r3) \
  x0 += x1; x1 = rotl32(x1, r0); x1 ^= x0; \
  x0 += x1; x1 = rotl32(x1, r1); x1 ^= x0; \
  x0 += x1; x1 = rotl32(x1, r2); x1 ^= x0; \
  x0 += x1; x1 = rotl32(x1, r3); x1 ^= x0;
  TFR4(13,15,26,6)  x0 += k1;  x1 += ks2 + 1u;
  TFR4(17,29,16,24) x0 += ks2; x1 += k0 + 2u;
  TFR4(13,15,26,6)  x0 += k0;  x1 += k1 + 3u;
  TFR4(17,29,16,24) x0 += k1;  x1 += ks2 + 4u;
  TFR4(13,15,26,6)  x0 += ks2; x1 += k0 + 5u;
#undef TFR4
  U2 r; r.a = x0; r.b = x1; return r;
}

__device__ __forceinline__ u32 rb32(u32 k0, u32 k1, u32 i){
  U2 r = tf2x32(k0, k1, 0u, i);
  return r.a ^ r.b;
}

__device__ __forceinline__ U2 split_key(u32 k0, u32 k1, u32 j){
  return tf2x32(k0, k1, 0u, j);
}

__device__ __forceinline__ float sigmoidf_(float x){ return 1.0f / (1.0f + expf(-x)); }
__device__ __forceinline__ float softplusf_(float x){ return fmaxf(x, 0.0f) + log1pf(expf(-fabsf(x))); }
__device__ __forceinline__ float leakyf_(float x){ return (x > 0.0f) ? x : 0.2f * x; }

__device__ __forceinline__ float erfinvf_(float x){
  float w = -log1pf(-x * x);
  float p;
  if (w < 5.0f){
    w -= 2.5f;
    p =               2.81022636e-08f;
    p = fmaf(p, w,    3.43273939e-07f);
    p = fmaf(p, w,   -3.5233877e-06f);
    p = fmaf(p, w,   -4.39150654e-06f);
    p = fmaf(p, w,    0.00021858087f);
    p = fmaf(p, w,   -0.00125372503f);
    p = fmaf(p, w,   -0.00417768164f);
    p = fmaf(p, w,    0.246640727f);
    p = fmaf(p, w,    1.50140941f);
  } else {
    w = sqrtf(w) - 3.0f;
    p =              -0.000200214257f;
    p = fmaf(p, w,    0.000100950558f);
    p = fmaf(p, w,    0.00134934322f);
    p = fmaf(p, w,   -0.00367342844f);
    p = fmaf(p, w,    0.00573950773f);
    p = fmaf(p, w,   -0.0076224613f);
    p = fmaf(p, w,    0.00943887047f);
    p = fmaf(p, w,    1.00167406f);
    p = fmaf(p, w,    2.83297682f);
  }
  return p * x;
}

__device__ __forceinline__ float uniform_from_bits(u32 bits){
  return __uint_as_float((bits >> 9) | 0x3f800000u) - 1.0f;
}

__device__ __forceinline__ float normal_from_bits(u32 bits){
  float u01 = uniform_from_bits(bits);
  const float lo = -0.99999994f;
  float v = fmaf(u01, 2.0f, lo);
  v = fmaxf(lo, v);
  return 1.41421356f * erfinvf_(v);
}

__device__ __forceinline__ int warp_idx_(int t, int wp, int sh){
  int tps = t + sh;
  int pos = (t >= wp) ? ((tps < Ld - 1) ? tps : (Ld - 1)) : t;
  int neg = ((t >= wp + sh) && (t < Ld + sh)) ? (t - sh) : t;
  return (sh > 0) ? pos : ((sh < 0) ? neg : t);
}

__device__ __forceinline__ u32 pack_bf16_2(float a, float b){
  u32 ua = __float_as_uint(a), ub = __float_as_uint(b);
  u32 ra = (ua + 0x7FFFu + ((ua >> 16) & 1u)) >> 16;
  u32 rb = (ub + 0x7FFFu + ((ub >> 16) & 1u)) >> 16;
  return (ra & 0xFFFFu) | (rb << 16);
}
__device__ __forceinline__ u16 f2bf(float a){
  u32 ua = __float_as_uint(a);
  return (u16)((ua + 0x7FFFu + ((ua >> 16) & 1u)) >> 16);
}
__device__ __forceinline__ float bf2f(u16 v){
  return __uint_as_float(((u32)v) << 16);
}

__device__ __forceinline__ int swz_(int v){
  return ((v >> 2) & 7) ^ ((v & 3) << 1);
}
__device__ __forceinline__ int rev9_(int k){
  return (int)(__brev((u32)k) >> 23);
}

// ---------------------------------------------------------------------------
// k_mlp: grid 8192. Every block computes the freq-mask byte row for
// pair = blockIdx.x = b*32 + jf (jf = even-feature index / 2):
//   for kk (=tid; tid0 also kk=256): draws at ck,cn,ck+1,cn+1 (validated
//   counters), byte = (k0a+k0b) | ((k1a+k1b)<<2)  -- m = 0.5*q exact.
// Blocks 0..255 additionally run the validated R8/R9 MLP row (b = blockIdx),
// and blocks 0/1 the wp/sh draws.
// ---------------------------------------------------------------------------
__global__ __launch_bounds__(256) void k_mlp(
    const float* __restrict__ w1, const float* __restrict__ b1,
    const float* __restrict__ w2, const float* __restrict__ b2,
    const float* __restrict__ w3, const float* __restrict__ b3,
    const float* __restrict__ wsc, const float* __restrict__ bsc,
    const float* __restrict__ p_scale, const float* __restrict__ p_shift,
    u16* __restrict__ h3b, float* __restrict__ scl,
    int* __restrict__ wp, int* __restrict__ shv,
    u8* __restrict__ fm)
{
  __shared__ float zs[64];
  __shared__ float h1s[128];
  __shared__ float h2s[256];
  __shared__ float hs[256];
  const int bid = blockIdx.x;
  const int n = threadIdx.x;

  // ---- freq-mask row (all 8192 blocks) ----
  {
    int fb = bid >> 5;           // batch row
    int jf = bid & 31;           // feature-pair index
    int fA = jf << 1;
    float s_shift = sigmoidf_(p_shift[0]);
    float s_mix = 1.0f - s_shift;
    float ratio = fminf(s_mix * 0.1f, 0.5f);
    U2 kf = split_key(0u, 42u, 4u);
    int nItr = (n == 0) ? 2 : 1;
    for (int e = 0; e < nItr; ++e){
      int kk = (e == 0) ? n : 256;
      int nk = (512 - kk) & 511;
      u32 ck = (u32)((fb * Ld + kk) * Fd + fA);
      u32 cn = (u32)((fb * Ld + nk) * Fd + fA);
      int k0a = (uniform_from_bits(rb32(kf.a, kf.b, ck))      > ratio) ? 1 : 0;
      int k0b = (uniform_from_bits(rb32(kf.a, kf.b, cn))      > ratio) ? 1 : 0;
      int k1a = (uniform_from_bits(rb32(kf.a, kf.b, ck + 1u)) > ratio) ? 1 : 0;
      int k1b = (uniform_from_bits(rb32(kf.a, kf.b, cn + 1u)) > ratio) ? 1 : 0;
      fm[(size_t)bid * 257 + kk] = (u8)((k0a + k0b) | ((k1a + k1b) << 2));
    }
  }

  if (bid >= 256) return;
  const int b = bid;

  if (n < 64){
    U2 kz = split_key(0u, 42u, 0u);
    zs[n] = normal_from_bits(rb32(kz.a, kz.b, (u32)(b * 64 + n)));
  }
  __syncthreads();

  if (n < 128){
    float acc = b1[n];
    #pragma unroll 8
    for (int k = 0; k < 64; ++k) acc = fmaf(zs[k], w1[k * 128 + n], acc);
    h1s[n] = leakyf_(acc);
  }
  __syncthreads();

  {
    float acc = b2[n];
    #pragma unroll 8
    for (int k = 0; k < 128; ++k) acc = fmaf(h1s[k], w2[k * 256 + n], acc);
    h2s[n] = leakyf_(acc);
  }
  __syncthreads();

  {
    float acc = b3[n];
    #pragma unroll 8
    for (int k = 0; k < 256; ++k) acc = fmaf(h2s[k], w3[k * 256 + n], acc);
    u16 hv = f2bf(leakyf_(acc));
    h3b[b * 256 + n] = hv;
    hs[n] = bf2f(hv);
  }
  __syncthreads();

  if (n < 64){
    float a2 = bsc[n];
    for (int k = 0; k < 256; ++k) a2 = fmaf(hs[k], wsc[k * 64 + n], a2);
    float s_scale = sigmoidf_(p_scale[0]);
    scl[b * 64 + n] = 1.0f + (softplusf_(a2) - 0.5f) * 0.2f * s_scale;
  }

  if (b < 2 && n < 128){
    int bb = b * 128 + n;
    float s_shift = sigmoidf_(p_shift[0]);
    int wsteps = (int)(51.2f * s_shift);
    U2 kwp = split_key(0u, 42u, 2u);
    U2 ksh = split_key(0u, 42u, 3u);
    {
      U2 k1 = split_key(kwp.a, kwp.b, 0u);
      U2 k2 = split_key(kwp.a, kwp.b, 1u);
      u32 hi = rb32(k1.a, k1.b, (u32)bb);
      u32 lo = rb32(k2.a, k2.b, (u32)bb);
      u32 span = (u32)(Ld - 2 * wsteps);
      u32 mult = 65536u % span; mult = (mult * mult) % span;
      u32 off = ((hi % span) * mult + (lo % span)) % span;
      wp[bb] = wsteps + (int)off;
    }
    {
      U2 k1 = split_key(ksh.a, ksh.b, 0u);
      U2 k2 = split_key(ksh.a, ksh.b, 1u);
      u32 hi = rb32(k1.a, k1.b, (u32)bb);
      u32 lo = rb32(k2.a, k2.b, (u32)bb);
      u32 span = (u32)(2 * wsteps + 1);
      u32 mult = 65536u % span; mult = (mult * mult) % span;
      u32 off = ((hi % span) * mult + (lo % span)) % span;
      shv[bb] = -wsteps + (int)off;
    }
  }
}

// ---------------------------------------------------------------------------
// k_gemm: byte-identical to validated R9.
// ---------------------------------------------------------------------------
typedef short short8 __attribute__((ext_vector_type(8)));
typedef float f32x4 __attribute__((ext_vector_type(4)));
union Frag { uint4 u; short8 s; };

__global__ __launch_bounds__(256, 2) void k_gemm(
    const u16* __restrict__ h3b,
    const float* __restrict__ wm, const float* __restrict__ bm,
    const float* __restrict__ wn, const float* __restrict__ bn,
    u32* __restrict__ mn)
{
  __shared__ __align__(16) u32 As [128 * 32];
  __shared__ __align__(16) u32 Bs0[128 * 32];
  __shared__ __align__(16) u32 Bs1[128 * 32];

  const int tid  = threadIdx.x;
  const int lane = tid & 63;
  const int w    = tid >> 6;
  const int q    = lane >> 4;
  const int lo   = lane & 15;
  const int nt0  = blockIdx.x << 7;
  const int b0   = blockIdx.y << 7;
  const int wr   = (w >> 1) << 6;
  const int wc   = (w & 1) << 6;

  const int p  = lane >> 3;
  const int c8 = lane & 7;
  const int nb = (w << 5) + (p << 2);

  f32x4 accm[4][4], accn[4][4];
  #pragma unroll
  for (int i = 0; i < 4; ++i)
    #pragma unroll
    for (int j = 0; j < 4; ++j){ accm[i][j] = (f32x4)0.0f; accn[i][j] = (f32x4)0.0f; }

  for (int kc = 0; kc < 256; kc += 64){
    if (kc) __syncthreads();
    #pragma unroll
    for (int j = 0; j < 4; ++j){
      int idx  = j * 256 + tid;
      int row  = idx >> 3;
      int slot = idx & 7;
      int g    = slot ^ swz_(row);
      uint4 v  = *(const uint4*)(h3b + (size_t)(b0 + row) * 256 + kc + g * 8);
      *(uint4*)&As[row * 32 + slot * 4] = v;
    }
    #pragma unroll
    for (int cp = 0; cp < 4; ++cp){
      int c = cp * 8 + c8;
      size_t gb = (size_t)(kc + 2 * c) * Nd + nt0 + nb;
      float4 m0 = *(const float4*)(wm + gb);
      float4 m1 = *(const float4*)(wm + gb + Nd);
      float4 v0 = *(const float4*)(wn + gb);
      float4 v1 = *(const float4*)(wn + gb + Nd);
      int g = c >> 2, cl = c & 3;
      #pragma unroll
      for (int s = 0; s < 4; ++s){
        int n = nb + s;
        int addr = n * 32 + (g ^ swz_(n)) * 4 + cl;
        float a0 = (s == 0) ? m0.x : (s == 1) ? m0.y : (s == 2) ? m0.z : m0.w;
        float a1 = (s == 0) ? m1.x : (s == 1) ? m1.y : (s == 2) ? m1.z : m1.w;
        float b0f = (s == 0) ? v0.x : (s == 1) ? v0.y : (s == 2) ? v0.z : v0.w;
        float b1f = (s == 0) ? v1.x : (s == 1) ? v1.y : (s == 2) ? v1.z : v1.w;
        Bs0[addr] = pack_bf16_2(a0, a1);
        Bs1[addr] = pack_bf16_2(b0f, b1f);
      }
    }
    __syncthreads();

    #pragma unroll
    for (int u = 0; u < 2; ++u){
      int G = u * 4 + q;
      Frag af[4], bfm[4], bfn[4];
      #pragma unroll
      for (int mt = 0; mt < 4; ++mt){
        int row = wr + mt * 16 + lo;
        af[mt].u = *(const uint4*)&As[row * 32 + (G ^ swz_(row)) * 4];
      }
      #pragma unroll
      for (int nt = 0; nt < 4; ++nt){
        int n = wc + nt * 16 + lo;
        int ad = n * 32 + (G ^ swz_(n)) * 4;
        bfm[nt].u = *(const uint4*)&Bs0[ad];
        bfn[nt].u = *(const uint4*)&Bs1[ad];
      }
      #pragma unroll
      for (int mt = 0; mt < 4; ++mt){
        #pragma unroll
        for (int nt = 0; nt < 4; ++nt){
          accm[mt][nt] = __builtin_amdgcn_mfma_f32_16x16x32_bf16(af[mt].s, bfm[nt].s, accm[mt][nt], 0, 0, 0);
          accn[mt][nt] = __builtin_amdgcn_mfma_f32_16x16x32_bf16(af[mt].s, bfn[nt].s, accn[mt][nt], 0, 0, 0);
        }
      }
    }
  }

  #pragma unroll
  for (int nt = 0; nt < 4; ++nt){
    int n = nt0 + wc + nt * 16 + lo;
    float bmv = bm[n];
    float bnv = bn[n];
    #pragma unroll
    for (int mt = 0; mt < 4; ++mt){
      #pragma unroll
      for (int r = 0; r < 4; ++r){
        int b = b0 + wr + mt * 16 + q * 4 + r;
        size_t o = (size_t)b * Nd + n;
        mn[o] = pack_bf16_2(accm[mt][nt][r] + bmv, accn[mt][nt][r] + bnv);
      }
    }
  }
}

// ---------------------------------------------------------------------------
// k_noise: byte-identical to validated R9 (in-place high-halfword transform).
// ---------------------------------------------------------------------------
__global__ __launch_bounds__(256) void k_noise(u32* __restrict__ mn,
                                               const float* __restrict__ p_noise){
  int gid = blockIdx.x * 256 + threadIdx.x;
  u32 base = (u32)gid * 8u;
  float s_noise = sigmoidf_(p_noise[0]);
  float sc = s_noise * 0.05f;
  U2 knk = split_key(0u, 42u, 1u);

  uint4 v0 = *(const uint4*)(mn + base);
  uint4 v1 = *(const uint4*)(mn + base + 4);
  u32 wds[8] = {v0.x, v0.y, v0.z, v0.w, v1.x, v1.y, v1.z, v1.w};
  #pragma unroll
  for (int h = 0; h < 8; ++h){
    u16 logit = (u16)(wds[h] >> 16);
    float nm = softplusf_(bf2f(logit));
    float nz = normal_from_bits(rb32(knk.a, knk.b, base + (u32)h));
    wds[h] = (wds[h] & 0xFFFFu) | ((u32)f2bf(nz * nm * sc) << 16);
  }
  *(uint4*)(mn + base)     = make_uint4(wds[0], wds[1], wds[2], wds[3]);
  *(uint4*)(mn + base + 4) = make_uint4(wds[4], wds[5], wds[6], wds[7]);
}

// ---------------------------------------------------------------------------
// k_faug: 4-series tile (2048 blocks), LDS ~19KB -> 8 blocks/CU. Same FFT
// butterfly expressions, same element->counter mapping; repack masks read
// from fm (byte -> m=0.5*q, exact). Epilogue identical to R9 (packed mn).
// ---------------------------------------------------------------------------
#define PITCH 529

__device__ __forceinline__ int lphys(int t){ return t + (t >> 5); }

__global__ __launch_bounds__(256, 6) void k_faug(
    const float* __restrict__ x,
    u32* mn,
    const float* __restrict__ scl,
    const int* __restrict__ wp, const int* __restrict__ shv,
    const u8* __restrict__ fm,
    const float* __restrict__ p_mask, const float* __restrict__ p_shift)
{
  __shared__ float SR[4 * PITCH];
  __shared__ float SI[4 * PITCH];
  __shared__ float2 tw[256];

  const int tid = threadIdx.x;
  const int b   = blockIdx.x >> 3;
  const int f0  = (blockIdx.x & 7) << 3;

  float s_mask  = sigmoidf_(p_mask[0]);
  float s_shift = sigmoidf_(p_shift[0]);
  float s_mix   = 1.0f - s_shift;
  float wa = 1.0f - s_mix - s_shift;
  wa = fminf(fmaxf(wa, 0.1f), 0.8f);
  float wb = s_mix * 0.5f;
  float wc = s_shift * 0.5f;
  float tot = wa + wb + wc;
  wa /= tot; wb /= tot; wc /= tot;
  bool pass = (s_mix < 0.01f);

  const int wpb = wp[b];
  const int shb = shv[b];

  {
    float ang = -6.283185307179586f * ((float)tid / 512.0f);
    tw[tid] = make_float2(cosf(ang), sinf(ang));
  }

  // ---- stage in + pack pairs (8 features -> 4 complex series) ----
  const float* xb = x + (size_t)b * Nd;
  #pragma unroll
  for (int s = 0; s < 4; ++s){
    int qq = (s << 8) + tid;        // float4 id, 0..1023
    int t  = qq >> 1;
    int f4 = qq & 1;
    float4 v = *(const float4*)(xb + t * 64 + f0 + (f4 << 2));
    int j = f4 << 1;
    int pt = lphys(t);
    SR[j * PITCH + pt]       = v.x;  SI[j * PITCH + pt]       = v.y;
    SR[(j + 1) * PITCH + pt] = v.z;  SI[(j + 1) * PITCH + pt] = v.w;
  }
  __syncthreads();

  // ---- forward DIF (natural in -> bitrev out) ----
  for (int s = 9; s >= 1; --s){
    int half = 1 << (s - 1);
    #pragma unroll
    for (int it = 0; it < 4; ++it){
      int j  = it;
      int bi = tid;
      int pos = bi & (half - 1);
      int g = bi >> (s - 1);
      int i1 = (g << s) + pos;
      int i2 = i1 + half;
      int a1 = j * PITCH + lphys(i1);
      int a2 = j * PITCH + lphys(i2);
      float ur = SR[a1], ui = SI[a1];
      float vr = SR[a2], vi = SI[a2];
      SR[a1] = ur + vr; SI[a1] = ui + vi;
      float dr = ur - vr, di = ui - vi;
      float2 w = tw[pos << (9 - s)];
      SR[a2] = dr * w.x - di * w.y;
      SI[a2] = dr * w.y + di * w.x;
    }
    __syncthreads();
  }

  // ---- masked Hermitian repack (masks from fm, decode exact) ----
  {
    const u8* fmb = fm + ((size_t)((b << 5) + (f0 >> 1))) * 257;
    #pragma unroll
    for (int it = 0; it < 4; ++it){
      int j = it;
      int k = tid;
      int nItr = (k == 0) ? 2 : 1;
      for (int e = 0; e < nItr; ++e){
        int kk = (e == 0) ? k : 256;
        int nk = (512 - kk) & 511;
        int pk = rev9_(kk), pn = rev9_(nk);
        int ak = j * PITCH + lphys(pk);
        int an = j * PITCH + lphys(pn);
        float zkr = SR[ak], zki = SI[ak];
        float znr = SR[an], zni = SI[an];
        float X0r = 0.5f * (zkr + znr), X0i = 0.5f * (zki - zni);
        float X1r = 0.5f * (zki + zni), X1i = 0.5f * (znr - zkr);
        u8 mq = fmb[j * 257 + kk];
        float m0 = 0.5f * (float)(mq & 3);
        float m1 = 0.5f * (float)(mq >> 2);
        SR[ak] = m0 * X0r - m1 * X1i;
        SI[ak] = m0 * X0i + m1 * X1r;
        SR[an] = m0 * X0r + m1 * X1i;
        SI[an] = m1 * X1r - m0 * X0i;
      }
    }
  }
  __syncthreads();

  // ---- inverse DIT (bitrev in -> natural out) ----
  for (int s = 1; s <= 9; ++s){
    int half = 1 << (s - 1);
    #pragma unroll
    for (int it = 0; it < 4; ++it){
      int j  = it;
      int bi = tid;
      int pos = bi & (half - 1);
      int g = bi >> (s - 1);
      int i1 = (g << s) + pos;
      int i2 = i1 + half;
      int a1 = j * PITCH + lphys(i1);
      int a2 = j * PITCH + lphys(i2);
      float2 w = tw[pos << (9 - s)];
      float vr = SR[a2], vi = SI[a2];
      float tx_ = vr * w.x + vi * w.y;    // v * conj(w)
      float ty_ = vi * w.x - vr * w.y;
      float ur = SR[a1], ui = SI[a1];
      SR[a1] = ur + tx_; SI[a1] = ui + ty_;
      SR[a2] = ur - tx_; SI[a2] = ui - ty_;
    }
    __syncthreads();
  }

  // ---- fused augmentation epilogue (packed in-place mn read/write) ----
  const float inv512 = 1.0f / 512.0f;
  u32* mnb = mn + (size_t)b * Nd;
  #pragma unroll
  for (int s = 0; s < 4; ++s){
    int qq = (s << 8) + tid;
    int t  = qq >> 1;
    int f4 = qq & 1;
    int f  = f0 + (f4 << 2);
    int j  = f4 << 1;
    int pt = lphys(t);
    int nidx = t * 64 + f;
    float4 xv = *(const float4*)(xb + nidx);
    int wi = warp_idx_(t, wpb, shb);
    float4 wv = *(const float4*)(xb + wi * 64 + f);
    float4 sc = *(const float4*)(scl + b * 64 + f);
    uint4 w4 = *(const uint4*)(mnb + nidx);
    float fr[4];
    fr[0] = SR[j * PITCH + pt] * inv512;
    fr[1] = SI[j * PITCH + pt] * inv512;
    fr[2] = SR[(j + 1) * PITCH + pt] * inv512;
    fr[3] = SI[(j + 1) * PITCH + pt] * inv512;
    const float xvv[4] = {xv.x, xv.y, xv.z, xv.w};
    const float wvv[4] = {wv.x, wv.y, wv.z, wv.w};
    const float scv[4] = {sc.x, sc.y, sc.z, sc.w};
    const u32 wdv[4] = {w4.x, w4.y, w4.z, w4.w};
    float o[4];
    #pragma unroll
    for (int c = 0; c < 4; ++c){
      float maskv = sigmoidf_(bf2f((u16)(wdv[c] & 0xFFFFu)));
      maskv = 1.0f - (1.0f - maskv) * s_mask * 0.3f;
      float noise = bf2f((u16)(wdv[c] >> 16));
      float fq = pass ? xvv[c] : fr[c];
      float aug = fmaf(xvv[c] * maskv, scv[c], noise);
      o[c] = aug * wa + fq * wb + wvv[c] * wc;
    }
    *(float4*)(mnb + nidx) = make_float4(o[0], o[1], o[2], o[3]);
  }
}

// ---------------------------------------------------------------------------
extern "C" void kernel_launch(void* const* d_in, const int* in_sizes, int n_in,
                              void* d_out, int out_size, void* d_ws, size_t ws_size,
                              hipStream_t stream)
{
  (void)in_sizes; (void)n_in; (void)out_size; (void)ws_size;
  const float* x   = (const float*)d_in[0];
  const float* w1  = (const float*)d_in[2];
  const float* b1  = (const float*)d_in[3];
  const float* w2  = (const float*)d_in[4];
  const float* b2  = (const float*)d_in[5];
  const float* w3  = (const float*)d_in[6];
  const float* b3  = (const float*)d_in[7];
  const float* wm  = (const float*)d_in[8];
  const float* bm  = (const float*)d_in[9];
  const float* wn  = (const float*)d_in[10];
  const float* bn  = (const float*)d_in[11];
  const float* wsc = (const float*)d_in[12];
  const float* bsc = (const float*)d_in[13];
  const float* pm  = (const float*)d_in[14];
  const float* pn  = (const float*)d_in[15];
  const float* psh = (const float*)d_in[16];
  const float* psc = (const float*)d_in[17];
  char* ws = (char*)d_ws;

  // ws: wp 1KB | shv 1KB+pad | h3b 128KB | scl 64KB | fm 2.06MB  (~2.3MB)
  int*   wp   = (int*)(ws + 0);
  int*   shv  = (int*)(ws + 1024);
  u16*   h3b  = (u16*)(ws + 4096);
  float* scl  = (float*)(ws + 4096 + 131072);
  u8*    fm   = (u8*) (ws + 4096 + 131072 + 65536);
  u32*   mn   = (u32*)d_out;

  k_mlp  <<<dim3(8192),    dim3(256), 0, stream>>>(w1, b1, w2, b2, w3, b3,
                                                   wsc, bsc, psc, psh,
                                                   h3b, scl, wp, shv, fm);
  k_gemm <<<dim3(256, 2),  dim3(256), 0, stream>>>(h3b, wm, bm, wn, bn, mn);
  k_noise<<<dim3(4096),    dim3(256), 0, stream>>>(mn, pn);
  k_faug <<<dim3(2048),    dim3(256), 0, stream>>>(x, mn, scl, wp, shv, fm,
                                                   pm, psh);
}

// Round 9
// 311.275 us; speedup vs baseline: 1.7454x; 1.0736x over previous
//
#include <hip/hip_runtime.h>
#include <cstdint>
#include <cstddef>

// ============================================================================
// MaskGenerator R13: best-of recombination.
//  - k_faug: R9's validated 16-feature tile (64B/row full-cacheline reads;
//    R12's 8-feature split caused 2x over-fetch -> HBM-bound 83us) PLUS
//    R12's validated fm mask-byte table (repack threefry hoisted to k_mlp).
//  - k_mlp: R12 validated (8192 blocks: freq-mask rows everywhere, MLP row
//    on blocks 0..255, wp/sh on blocks 0/1).
//  - k_gemm, k_noise: byte-identical validated R9. mn packed in d_out (R9).
// All numerics bit-identical to R12 (absmax 0.015625).
// ============================================================================

typedef unsigned int u32;
typedef unsigned short u16;
typedef unsigned char u8;

#define Bd 256
#define Ld 512
#define Fd 64
#define Nd 32768            // Ld*Fd

struct U2 { u32 a, b; };

__device__ __forceinline__ u32 rotl32(u32 x, int r){ return (x << r) | (x >> (32 - r)); }

__device__ __forceinline__ U2 tf2x32(u32 k0, u32 k1, u32 x0, u32 x1){
  u32 ks2 = k0 ^ k1 ^ 0x1BD11BDAu;
  x0 += k0; x1 += k1;
#define TFR4(r0,r1,r2,r3) \
  x0 += x1; x1 = rotl32(x1, r0); x1 ^= x0; \
  x0 += x1; x1 = rotl32(x1, r1); x1 ^= x0; \
  x0 += x1; x1 = rotl32(x1, r2); x1 ^= x0; \
  x0 += x1; x1 = rotl32(x1, r3); x1 ^= x0;
  TFR4(13,15,26,6)  x0 += k1;  x1 += ks2 + 1u;
  TFR4(17,29,16,24) x0 += ks2; x1 += k0 + 2u;
  TFR4(13,15,26,6)  x0 += k0;  x1 += k1 + 3u;
  TFR4(17,29,16,24) x0 += k1;  x1 += ks2 + 4u;
  TFR4(13,15,26,6)  x0 += ks2; x1 += k0 + 5u;
#undef TFR4
  U2 r; r.a = x0; r.b = x1; return r;
}

__device__ __forceinline__ u32 rb32(u32 k0, u32 k1, u32 i){
  U2 r = tf2x32(k0, k1, 0u, i);
  return r.a ^ r.b;
}

__device__ __forceinline__ U2 split_key(u32 k0, u32 k1, u32 j){
  return tf2x32(k0, k1, 0u, j);
}

__device__ __forceinline__ float sigmoidf_(float x){ return 1.0f / (1.0f + expf(-x)); }
__device__ __forceinline__ float softplusf_(float x){ return fmaxf(x, 0.0f) + log1pf(expf(-fabsf(x))); }
__device__ __forceinline__ float leakyf_(float x){ return (x > 0.0f) ? x : 0.2f * x; }

__device__ __forceinline__ float erfinvf_(float x){
  float w = -log1pf(-x * x);
  float p;
  if (w < 5.0f){
    w -= 2.5f;
    p =               2.81022636e-08f;
    p = fmaf(p, w,    3.43273939e-07f);
    p = fmaf(p, w,   -3.5233877e-06f);
    p = fmaf(p, w,   -4.39150654e-06f);
    p = fmaf(p, w,    0.00021858087f);
    p = fmaf(p, w,   -0.00125372503f);
    p = fmaf(p, w,   -0.00417768164f);
    p = fmaf(p, w,    0.246640727f);
    p = fmaf(p, w,    1.50140941f);
  } else {
    w = sqrtf(w) - 3.0f;
    p =              -0.000200214257f;
    p = fmaf(p, w,    0.000100950558f);
    p = fmaf(p, w,    0.00134934322f);
    p = fmaf(p, w,   -0.00367342844f);
    p = fmaf(p, w,    0.00573950773f);
    p = fmaf(p, w,   -0.0076224613f);
    p = fmaf(p, w,    0.00943887047f);
    p = fmaf(p, w,    1.00167406f);
    p = fmaf(p, w,    2.83297682f);
  }
  return p * x;
}

__device__ __forceinline__ float uniform_from_bits(u32 bits){
  return __uint_as_float((bits >> 9) | 0x3f800000u) - 1.0f;
}

__device__ __forceinline__ float normal_from_bits(u32 bits){
  float u01 = uniform_from_bits(bits);
  const float lo = -0.99999994f;
  float v = fmaf(u01, 2.0f, lo);
  v = fmaxf(lo, v);
  return 1.41421356f * erfinvf_(v);
}

__device__ __forceinline__ int warp_idx_(int t, int wp, int sh){
  int tps = t + sh;
  int pos = (t >= wp) ? ((tps < Ld - 1) ? tps : (Ld - 1)) : t;
  int neg = ((t >= wp + sh) && (t < Ld + sh)) ? (t - sh) : t;
  return (sh > 0) ? pos : ((sh < 0) ? neg : t);
}

__device__ __forceinline__ u32 pack_bf16_2(float a, float b){
  u32 ua = __float_as_uint(a), ub = __float_as_uint(b);
  u32 ra = (ua + 0x7FFFu + ((ua >> 16) & 1u)) >> 16;
  u32 rb = (ub + 0x7FFFu + ((ub >> 16) & 1u)) >> 16;
  return (ra & 0xFFFFu) | (rb << 16);
}
__device__ __forceinline__ u16 f2bf(float a){
  u32 ua = __float_as_uint(a);
  return (u16)((ua + 0x7FFFu + ((ua >> 16) & 1u)) >> 16);
}
__device__ __forceinline__ float bf2f(u16 v){
  return __uint_as_float(((u32)v) << 16);
}

__device__ __forceinline__ int swz_(int v){
  return ((v >> 2) & 7) ^ ((v & 3) << 1);
}
__device__ __forceinline__ int rev9_(int k){
  return (int)(__brev((u32)k) >> 23);
}

// ---------------------------------------------------------------------------
// k_mlp: validated R12. Grid 8192: every block computes one freq-mask byte
// row (pair = b*32 + jf); blocks 0..255 also run the MLP row; blocks 0/1 the
// wp/sh draws. All counters identical to the original in-k_faug draws.
// ---------------------------------------------------------------------------
__global__ __launch_bounds__(256) void k_mlp(
    const float* __restrict__ w1, const float* __restrict__ b1,
    const float* __restrict__ w2, const float* __restrict__ b2,
    const float* __restrict__ w3, const float* __restrict__ b3,
    const float* __restrict__ wsc, const float* __restrict__ bsc,
    const float* __restrict__ p_scale, const float* __restrict__ p_shift,
    u16* __restrict__ h3b, float* __restrict__ scl,
    int* __restrict__ wp, int* __restrict__ shv,
    u8* __restrict__ fm)
{
  __shared__ float zs[64];
  __shared__ float h1s[128];
  __shared__ float h2s[256];
  __shared__ float hs[256];
  const int bid = blockIdx.x;
  const int n = threadIdx.x;

  // ---- freq-mask row (all 8192 blocks) ----
  {
    int fb = bid >> 5;           // batch row
    int jf = bid & 31;           // feature-pair index
    int fA = jf << 1;
    float s_shift = sigmoidf_(p_shift[0]);
    float s_mix = 1.0f - s_shift;
    float ratio = fminf(s_mix * 0.1f, 0.5f);
    U2 kf = split_key(0u, 42u, 4u);
    int nItr = (n == 0) ? 2 : 1;
    for (int e = 0; e < nItr; ++e){
      int kk = (e == 0) ? n : 256;
      int nk = (512 - kk) & 511;
      u32 ck = (u32)((fb * Ld + kk) * Fd + fA);
      u32 cn = (u32)((fb * Ld + nk) * Fd + fA);
      int k0a = (uniform_from_bits(rb32(kf.a, kf.b, ck))      > ratio) ? 1 : 0;
      int k0b = (uniform_from_bits(rb32(kf.a, kf.b, cn))      > ratio) ? 1 : 0;
      int k1a = (uniform_from_bits(rb32(kf.a, kf.b, ck + 1u)) > ratio) ? 1 : 0;
      int k1b = (uniform_from_bits(rb32(kf.a, kf.b, cn + 1u)) > ratio) ? 1 : 0;
      fm[(size_t)bid * 257 + kk] = (u8)((k0a + k0b) | ((k1a + k1b) << 2));
    }
  }

  if (bid >= 256) return;
  const int b = bid;

  if (n < 64){
    U2 kz = split_key(0u, 42u, 0u);
    zs[n] = normal_from_bits(rb32(kz.a, kz.b, (u32)(b * 64 + n)));
  }
  __syncthreads();

  if (n < 128){
    float acc = b1[n];
    #pragma unroll 8
    for (int k = 0; k < 64; ++k) acc = fmaf(zs[k], w1[k * 128 + n], acc);
    h1s[n] = leakyf_(acc);
  }
  __syncthreads();

  {
    float acc = b2[n];
    #pragma unroll 8
    for (int k = 0; k < 128; ++k) acc = fmaf(h1s[k], w2[k * 256 + n], acc);
    h2s[n] = leakyf_(acc);
  }
  __syncthreads();

  {
    float acc = b3[n];
    #pragma unroll 8
    for (int k = 0; k < 256; ++k) acc = fmaf(h2s[k], w3[k * 256 + n], acc);
    u16 hv = f2bf(leakyf_(acc));
    h3b[b * 256 + n] = hv;
    hs[n] = bf2f(hv);
  }
  __syncthreads();

  if (n < 64){
    float a2 = bsc[n];
    for (int k = 0; k < 256; ++k) a2 = fmaf(hs[k], wsc[k * 64 + n], a2);
    float s_scale = sigmoidf_(p_scale[0]);
    scl[b * 64 + n] = 1.0f + (softplusf_(a2) - 0.5f) * 0.2f * s_scale;
  }

  if (b < 2 && n < 128){
    int bb = b * 128 + n;
    float s_shift = sigmoidf_(p_shift[0]);
    int wsteps = (int)(51.2f * s_shift);
    U2 kwp = split_key(0u, 42u, 2u);
    U2 ksh = split_key(0u, 42u, 3u);
    {
      U2 k1 = split_key(kwp.a, kwp.b, 0u);
      U2 k2 = split_key(kwp.a, kwp.b, 1u);
      u32 hi = rb32(k1.a, k1.b, (u32)bb);
      u32 lo = rb32(k2.a, k2.b, (u32)bb);
      u32 span = (u32)(Ld - 2 * wsteps);
      u32 mult = 65536u % span; mult = (mult * mult) % span;
      u32 off = ((hi % span) * mult + (lo % span)) % span;
      wp[bb] = wsteps + (int)off;
    }
    {
      U2 k1 = split_key(ksh.a, ksh.b, 0u);
      U2 k2 = split_key(ksh.a, ksh.b, 1u);
      u32 hi = rb32(k1.a, k1.b, (u32)bb);
      u32 lo = rb32(k2.a, k2.b, (u32)bb);
      u32 span = (u32)(2 * wsteps + 1);
      u32 mult = 65536u % span; mult = (mult * mult) % span;
      u32 off = ((hi % span) * mult + (lo % span)) % span;
      shv[bb] = -wsteps + (int)off;
    }
  }
}

// ---------------------------------------------------------------------------
// k_gemm: byte-identical to validated R9.
// ---------------------------------------------------------------------------
typedef short short8 __attribute__((ext_vector_type(8)));
typedef float f32x4 __attribute__((ext_vector_type(4)));
union Frag { uint4 u; short8 s; };

__global__ __launch_bounds__(256, 2) void k_gemm(
    const u16* __restrict__ h3b,
    const float* __restrict__ wm, const float* __restrict__ bm,
    const float* __restrict__ wn, const float* __restrict__ bn,
    u32* __restrict__ mn)
{
  __shared__ __align__(16) u32 As [128 * 32];
  __shared__ __align__(16) u32 Bs0[128 * 32];
  __shared__ __align__(16) u32 Bs1[128 * 32];

  const int tid  = threadIdx.x;
  const int lane = tid & 63;
  const int w    = tid >> 6;
  const int q    = lane >> 4;
  const int lo   = lane & 15;
  const int nt0  = blockIdx.x << 7;
  const int b0   = blockIdx.y << 7;
  const int wr   = (w >> 1) << 6;
  const int wc   = (w & 1) << 6;

  const int p  = lane >> 3;
  const int c8 = lane & 7;
  const int nb = (w << 5) + (p << 2);

  f32x4 accm[4][4], accn[4][4];
  #pragma unroll
  for (int i = 0; i < 4; ++i)
    #pragma unroll
    for (int j = 0; j < 4; ++j){ accm[i][j] = (f32x4)0.0f; accn[i][j] = (f32x4)0.0f; }

  for (int kc = 0; kc < 256; kc += 64){
    if (kc) __syncthreads();
    #pragma unroll
    for (int j = 0; j < 4; ++j){
      int idx  = j * 256 + tid;
      int row  = idx >> 3;
      int slot = idx & 7;
      int g    = slot ^ swz_(row);
      uint4 v  = *(const uint4*)(h3b + (size_t)(b0 + row) * 256 + kc + g * 8);
      *(uint4*)&As[row * 32 + slot * 4] = v;
    }
    #pragma unroll
    for (int cp = 0; cp < 4; ++cp){
      int c = cp * 8 + c8;
      size_t gb = (size_t)(kc + 2 * c) * Nd + nt0 + nb;
      float4 m0 = *(const float4*)(wm + gb);
      float4 m1 = *(const float4*)(wm + gb + Nd);
      float4 v0 = *(const float4*)(wn + gb);
      float4 v1 = *(const float4*)(wn + gb + Nd);
      int g = c >> 2, cl = c & 3;
      #pragma unroll
      for (int s = 0; s < 4; ++s){
        int n = nb + s;
        int addr = n * 32 + (g ^ swz_(n)) * 4 + cl;
        float a0 = (s == 0) ? m0.x : (s == 1) ? m0.y : (s == 2) ? m0.z : m0.w;
        float a1 = (s == 0) ? m1.x : (s == 1) ? m1.y : (s == 2) ? m1.z : m1.w;
        float b0f = (s == 0) ? v0.x : (s == 1) ? v0.y : (s == 2) ? v0.z : v0.w;
        float b1f = (s == 0) ? v1.x : (s == 1) ? v1.y : (s == 2) ? v1.z : v1.w;
        Bs0[addr] = pack_bf16_2(a0, a1);
        Bs1[addr] = pack_bf16_2(b0f, b1f);
      }
    }
    __syncthreads();

    #pragma unroll
    for (int u = 0; u < 2; ++u){
      int G = u * 4 + q;
      Frag af[4], bfm[4], bfn[4];
      #pragma unroll
      for (int mt = 0; mt < 4; ++mt){
        int row = wr + mt * 16 + lo;
        af[mt].u = *(const uint4*)&As[row * 32 + (G ^ swz_(row)) * 4];
      }
      #pragma unroll
      for (int nt = 0; nt < 4; ++nt){
        int n = wc + nt * 16 + lo;
        int ad = n * 32 + (G ^ swz_(n)) * 4;
        bfm[nt].u = *(const uint4*)&Bs0[ad];
        bfn[nt].u = *(const uint4*)&Bs1[ad];
      }
      #pragma unroll
      for (int mt = 0; mt < 4; ++mt){
        #pragma unroll
        for (int nt = 0; nt < 4; ++nt){
          accm[mt][nt] = __builtin_amdgcn_mfma_f32_16x16x32_bf16(af[mt].s, bfm[nt].s, accm[mt][nt], 0, 0, 0);
          accn[mt][nt] = __builtin_amdgcn_mfma_f32_16x16x32_bf16(af[mt].s, bfn[nt].s, accn[mt][nt], 0, 0, 0);
        }
      }
    }
  }

  #pragma unroll
  for (int nt = 0; nt < 4; ++nt){
    int n = nt0 + wc + nt * 16 + lo;
    float bmv = bm[n];
    float bnv = bn[n];
    #pragma unroll
    for (int mt = 0; mt < 4; ++mt){
      #pragma unroll
      for (int r = 0; r < 4; ++r){
        int b = b0 + wr + mt * 16 + q * 4 + r;
        size_t o = (size_t)b * Nd + n;
        mn[o] = pack_bf16_2(accm[mt][nt][r] + bmv, accn[mt][nt][r] + bnv);
      }
    }
  }
}

// ---------------------------------------------------------------------------
// k_noise: byte-identical to validated R9 (in-place high-halfword transform).
// ---------------------------------------------------------------------------
__global__ __launch_bounds__(256) void k_noise(u32* __restrict__ mn,
                                               const float* __restrict__ p_noise){
  int gid = blockIdx.x * 256 + threadIdx.x;
  u32 base = (u32)gid * 8u;
  float s_noise = sigmoidf_(p_noise[0]);
  float sc = s_noise * 0.05f;
  U2 knk = split_key(0u, 42u, 1u);

  uint4 v0 = *(const uint4*)(mn + base);
  uint4 v1 = *(const uint4*)(mn + base + 4);
  u32 wds[8] = {v0.x, v0.y, v0.z, v0.w, v1.x, v1.y, v1.z, v1.w};
  #pragma unroll
  for (int h = 0; h < 8; ++h){
    u16 logit = (u16)(wds[h] >> 16);
    float nm = softplusf_(bf2f(logit));
    float nz = normal_from_bits(rb32(knk.a, knk.b, base + (u32)h));
    wds[h] = (wds[h] & 0xFFFFu) | ((u32)f2bf(nz * nm * sc) << 16);
  }
  *(uint4*)(mn + base)     = make_uint4(wds[0], wds[1], wds[2], wds[3]);
  *(uint4*)(mn + base + 4) = make_uint4(wds[4], wds[5], wds[6], wds[7]);
}

// ---------------------------------------------------------------------------
// k_faug: R9 geometry (16-feature tile, 8 complex series, PITCH 529, 1024
// blocks, 4/CU) with R12's fm mask-byte repack (decode m = 0.5f*q, exact).
// Epilogue identical to R9 (packed mn in-place read/write).
// ---------------------------------------------------------------------------
#define PITCH 529

__device__ __forceinline__ int lphys(int t){ return t + (t >> 5); }

__global__ __launch_bounds__(256, 4) void k_faug(
    const float* __restrict__ x,
    u32* mn,
    const float* __restrict__ scl,
    const int* __restrict__ wp, const int* __restrict__ shv,
    const u8* __restrict__ fm,
    const float* __restrict__ p_mask, const float* __restrict__ p_shift)
{
  __shared__ float SR[8 * PITCH];
  __shared__ float SI[8 * PITCH];
  __shared__ float2 tw[256];

  const int tid = threadIdx.x;
  const int b   = blockIdx.x >> 2;
  const int f0  = (blockIdx.x & 3) << 4;

  float s_mask  = sigmoidf_(p_mask[0]);
  float s_shift = sigmoidf_(p_shift[0]);
  float s_mix   = 1.0f - s_shift;
  float wa = 1.0f - s_mix - s_shift;
  wa = fminf(fmaxf(wa, 0.1f), 0.8f);
  float wb = s_mix * 0.5f;
  float wc = s_shift * 0.5f;
  float tot = wa + wb + wc;
  wa /= tot; wb /= tot; wc /= tot;
  bool pass = (s_mix < 0.01f);

  const int wpb = wp[b];
  const int shb = shv[b];

  {
    float ang = -6.283185307179586f * ((float)tid / 512.0f);
    tw[tid] = make_float2(cosf(ang), sinf(ang));
  }

  // ---- stage in + pack pairs ----
  const float* xb = x + (size_t)b * Nd;
  #pragma unroll
  for (int s = 0; s < 8; ++s){
    int qq = (s << 8) + tid;        // float4 id, 0..2047
    int t  = qq >> 2;
    int f4 = qq & 3;
    float4 v = *(const float4*)(xb + t * 64 + f0 + (f4 << 2));
    int j = f4 << 1;
    int pt = lphys(t);
    SR[j * PITCH + pt]       = v.x;  SI[j * PITCH + pt]       = v.y;
    SR[(j + 1) * PITCH + pt] = v.z;  SI[(j + 1) * PITCH + pt] = v.w;
  }
  __syncthreads();

  // ---- forward DIF (natural in -> bitrev out) ----
  for (int s = 9; s >= 1; --s){
    int half = 1 << (s - 1);
    #pragma unroll
    for (int it = 0; it < 8; ++it){
      int j  = it;
      int bi = tid;
      int pos = bi & (half - 1);
      int g = bi >> (s - 1);
      int i1 = (g << s) + pos;
      int i2 = i1 + half;
      int a1 = j * PITCH + lphys(i1);
      int a2 = j * PITCH + lphys(i2);
      float ur = SR[a1], ui = SI[a1];
      float vr = SR[a2], vi = SI[a2];
      SR[a1] = ur + vr; SI[a1] = ui + vi;
      float dr = ur - vr, di = ui - vi;
      float2 w = tw[pos << (9 - s)];
      SR[a2] = dr * w.x - di * w.y;
      SI[a2] = dr * w.y + di * w.x;
    }
    __syncthreads();
  }

  // ---- masked Hermitian repack (masks from fm, decode exact) ----
  {
    const u8* fmb = fm + ((size_t)((b << 5) + (f0 >> 1))) * 257;
    #pragma unroll
    for (int it = 0; it < 8; ++it){
      int j = it;
      int k = tid;
      int nItr = (k == 0) ? 2 : 1;
      for (int e = 0; e < nItr; ++e){
        int kk = (e == 0) ? k : 256;
        int nk = (512 - kk) & 511;
        int pk = rev9_(kk), pn = rev9_(nk);
        int ak = j * PITCH + lphys(pk);
        int an = j * PITCH + lphys(pn);
        float zkr = SR[ak], zki = SI[ak];
        float znr = SR[an], zni = SI[an];
        float X0r = 0.5f * (zkr + znr), X0i = 0.5f * (zki - zni);
        float X1r = 0.5f * (zki + zni), X1i = 0.5f * (znr - zkr);
        u8 mq = fmb[j * 257 + kk];
        float m0 = 0.5f * (float)(mq & 3);
        float m1 = 0.5f * (float)(mq >> 2);
        SR[ak] = m0 * X0r - m1 * X1i;
        SI[ak] = m0 * X0i + m1 * X1r;
        SR[an] = m0 * X0r + m1 * X1i;
        SI[an] = m1 * X1r - m0 * X0i;
      }
    }
  }
  __syncthreads();

  // ---- inverse DIT (bitrev in -> natural out) ----
  for (int s = 1; s <= 9; ++s){
    int half = 1 << (s - 1);
    #pragma unroll
    for (int it = 0; it < 8; ++it){
      int j  = it;
      int bi = tid;
      int pos = bi & (half - 1);
      int g = bi >> (s - 1);
      int i1 = (g << s) + pos;
      int i2 = i1 + half;
      int a1 = j * PITCH + lphys(i1);
      int a2 = j * PITCH + lphys(i2);
      float2 w = tw[pos << (9 - s)];
      float vr = SR[a2], vi = SI[a2];
      float tx_ = vr * w.x + vi * w.y;    // v * conj(w)
      float ty_ = vi * w.x - vr * w.y;
      float ur = SR[a1], ui = SI[a1];
      SR[a1] = ur + tx_; SI[a1] = ui + ty_;
      SR[a2] = ur - tx_; SI[a2] = ui - ty_;
    }
    __syncthreads();
  }

  // ---- fused augmentation epilogue (packed in-place mn read/write) ----
  const float inv512 = 1.0f / 512.0f;
  u32* mnb = mn + (size_t)b * Nd;
  #pragma unroll
  for (int s = 0; s < 8; ++s){
    int qq = (s << 8) + tid;
    int t  = qq >> 2;
    int f4 = qq & 3;
    int f  = f0 + (f4 << 2);
    int j  = f4 << 1;
    int pt = lphys(t);
    int nidx = t * 64 + f;
    float4 xv = *(const float4*)(xb + nidx);
    int wi = warp_idx_(t, wpb, shb);
    float4 wv = *(const float4*)(xb + wi * 64 + f);
    float4 sc = *(const float4*)(scl + b * 64 + f);
    uint4 w4 = *(const uint4*)(mnb + nidx);
    float fr[4];
    fr[0] = SR[j * PITCH + pt] * inv512;
    fr[1] = SI[j * PITCH + pt] * inv512;
    fr[2] = SR[(j + 1) * PITCH + pt] * inv512;
    fr[3] = SI[(j + 1) * PITCH + pt] * inv512;
    const float xvv[4] = {xv.x, xv.y, xv.z, xv.w};
    const float wvv[4] = {wv.x, wv.y, wv.z, wv.w};
    const float scv[4] = {sc.x, sc.y, sc.z, sc.w};
    const u32 wdv[4] = {w4.x, w4.y, w4.z, w4.w};
    float o[4];
    #pragma unroll
    for (int c = 0; c < 4; ++c){
      float maskv = sigmoidf_(bf2f((u16)(wdv[c] & 0xFFFFu)));
      maskv = 1.0f - (1.0f - maskv) * s_mask * 0.3f;
      float noise = bf2f((u16)(wdv[c] >> 16));
      float fq = pass ? xvv[c] : fr[c];
      float aug = fmaf(xvv[c] * maskv, scv[c], noise);
      o[c] = aug * wa + fq * wb + wvv[c] * wc;
    }
    *(float4*)(mnb + nidx) = make_float4(o[0], o[1], o[2], o[3]);
  }
}

// ---------------------------------------------------------------------------
extern "C" void kernel_launch(void* const* d_in, const int* in_sizes, int n_in,
                              void* d_out, int out_size, void* d_ws, size_t ws_size,
                              hipStream_t stream)
{
  (void)in_sizes; (void)n_in; (void)out_size; (void)ws_size;
  const float* x   = (const float*)d_in[0];
  const float* w1  = (const float*)d_in[2];
  const float* b1  = (const float*)d_in[3];
  const float* w2  = (const float*)d_in[4];
  const float* b2  = (const float*)d_in[5];
  const float* w3  = (const float*)d_in[6];
  const float* b3  = (const float*)d_in[7];
  const float* wm  = (const float*)d_in[8];
  const float* bm  = (const float*)d_in[9];
  const float* wn  = (const float*)d_in[10];
  const float* bn  = (const float*)d_in[11];
  const float* wsc = (const float*)d_in[12];
  const float* bsc = (const float*)d_in[13];
  const float* pm  = (const float*)d_in[14];
  const float* pn  = (const float*)d_in[15];
  const float* psh = (const float*)d_in[16];
  const float* psc = (const float*)d_in[17];
  char* ws = (char*)d_ws;

  // ws: wp 1KB | shv 1KB+pad | h3b 128KB | scl 64KB | fm 2.06MB  (~2.3MB)
  int*   wp   = (int*)(ws + 0);
  int*   shv  = (int*)(ws + 1024);
  u16*   h3b  = (u16*)(ws + 4096);
  float* scl  = (float*)(ws + 4096 + 131072);
  u8*    fm   = (u8*) (ws + 4096 + 131072 + 65536);
  u32*   mn   = (u32*)d_out;

  k_mlp  <<<dim3(8192),    dim3(256), 0, stream>>>(w1, b1, w2, b2, w3, b3,
                                                   wsc, bsc, psc, psh,
                                                   h3b, scl, wp, shv, fm);
  k_gemm <<<dim3(256, 2),  dim3(256), 0, stream>>>(h3b, wm, bm, wn, bn, mn);
  k_noise<<<dim3(4096),    dim3(256), 0, stream>>>(mn, pn);
  k_faug <<<dim3(1024),    dim3(256), 0, stream>>>(x, mn, scl, wp, shv, fm,
                                                   pm, psh);
}

// Round 10
// 274.759 us; speedup vs baseline: 1.9774x; 1.1329x over previous
//
#include <hip/hip_runtime.h>
#include <cstdint>
#include <cstddef>

// ============================================================================
// MaskGenerator R14: R13 structure (311us, best) + native-transcendental
// k_noise. rocprof R13: k_noise = 66us @ VALUBusy ~100% -- pure VALU issue
// floor, ~600 instr/elem, dominated by precise OCML expf/log1pf expansions.
// Replace with 1-instruction v_exp_f32/v_log_f32 paths (__expf/__logf):
//   log1pf(y) -> __logf(1+y)  (operand already rounded -> no cancellation)
//   expf      -> __expf
// Same polynomial/branch/counters; nz/nmag error ~1e-6 rel; noise enters
// output scaled ~0.02 -> ~1e-7 output perturbation. Same for k_faug's
// per-element mask sigmoid. NOT touched: k_mlp mask draws (discrete
// boundary-flip risk), scalar param sigmoids, wa/wb/wc, threefry counters.
// k_mlp / k_gemm / k_noise-structure / k_faug-geometry: validated R13.
// ============================================================================

typedef unsigned int u32;
typedef unsigned short u16;
typedef unsigned char u8;

#define Bd 256
#define Ld 512
#define Fd 64
#define Nd 32768            // Ld*Fd

struct U2 { u32 a, b; };

__device__ __forceinline__ u32 rotl32(u32 x, int r){ return (x << r) | (x >> (32 - r)); }

__device__ __forceinline__ U2 tf2x32(u32 k0, u32 k1, u32 x0, u32 x1){
  u32 ks2 = k0 ^ k1 ^ 0x1BD11BDAu;
  x0 += k0; x1 += k1;
#define TFR4(r0,r1,r2,r3) \
  x0 += x1; x1 = rotl32(x1, r0); x1 ^= x0; \
  x0 += x1; x1 = rotl32(x1, r1); x1 ^= x0; \
  x0 += x1; x1 = rotl32(x1, r2); x1 ^= x0; \
  x0 += x1; x1 = rotl32(x1, r3); x1 ^= x0;
  TFR4(13,15,26,6)  x0 += k1;  x1 += ks2 + 1u;
  TFR4(17,29,16,24) x0 += ks2; x1 += k0 + 2u;
  TFR4(13,15,26,6)  x0 += k0;  x1 += k1 + 3u;
  TFR4(17,29,16,24) x0 += k1;  x1 += ks2 + 4u;
  TFR4(13,15,26,6)  x0 += ks2; x1 += k0 + 5u;
#undef TFR4
  U2 r; r.a = x0; r.b = x1; return r;
}

__device__ __forceinline__ u32 rb32(u32 k0, u32 k1, u32 i){
  U2 r = tf2x32(k0, k1, 0u, i);
  return r.a ^ r.b;
}

__device__ __forceinline__ U2 split_key(u32 k0, u32 k1, u32 j){
  return tf2x32(k0, k1, 0u, j);
}

__device__ __forceinline__ float sigmoidf_(float x){ return 1.0f / (1.0f + expf(-x)); }
__device__ __forceinline__ float softplusf_(float x){ return fmaxf(x, 0.0f) + log1pf(expf(-fabsf(x))); }
__device__ __forceinline__ float leakyf_(float x){ return (x > 0.0f) ? x : 0.2f * x; }

// ---- fast (native v_exp_f32 / v_log_f32) variants: k_noise + k_faug epilogue
__device__ __forceinline__ float sigmoid_fast_(float x){
  return 1.0f / (1.0f + __expf(-x));
}
__device__ __forceinline__ float softplus_fast_(float x){
  return fmaxf(x, 0.0f) + __logf(1.0f + __expf(-fabsf(x)));
}

__device__ __forceinline__ float erfinvf_(float x){
  float w = -log1pf(-x * x);
  float p;
  if (w < 5.0f){
    w -= 2.5f;
    p =               2.81022636e-08f;
    p = fmaf(p, w,    3.43273939e-07f);
    p = fmaf(p, w,   -3.5233877e-06f);
    p = fmaf(p, w,   -4.39150654e-06f);
    p = fmaf(p, w,    0.00021858087f);
    p = fmaf(p, w,   -0.00125372503f);
    p = fmaf(p, w,   -0.00417768164f);
    p = fmaf(p, w,    0.246640727f);
    p = fmaf(p, w,    1.50140941f);
  } else {
    w = sqrtf(w) - 3.0f;
    p =              -0.000200214257f;
    p = fmaf(p, w,    0.000100950558f);
    p = fmaf(p, w,    0.00134934322f);
    p = fmaf(p, w,   -0.00367342844f);
    p = fmaf(p, w,    0.00573950773f);
    p = fmaf(p, w,   -0.0076224613f);
    p = fmaf(p, w,    0.00943887047f);
    p = fmaf(p, w,    1.00167406f);
    p = fmaf(p, w,    2.83297682f);
  }
  return p * x;
}

__device__ __forceinline__ float erfinv_fast_(float x){
  float t = x * x;
  float w = -__logf(1.0f - t);      // t already rounded -> 1-t Sterbenz-exact
  float p;
  if (w < 5.0f){
    w -= 2.5f;
    p =               2.81022636e-08f;
    p = fmaf(p, w,    3.43273939e-07f);
    p = fmaf(p, w,   -3.5233877e-06f);
    p = fmaf(p, w,   -4.39150654e-06f);
    p = fmaf(p, w,    0.00021858087f);
    p = fmaf(p, w,   -0.00125372503f);
    p = fmaf(p, w,   -0.00417768164f);
    p = fmaf(p, w,    0.246640727f);
    p = fmaf(p, w,    1.50140941f);
  } else {
    w = sqrtf(w) - 3.0f;
    p =              -0.000200214257f;
    p = fmaf(p, w,    0.000100950558f);
    p = fmaf(p, w,    0.00134934322f);
    p = fmaf(p, w,   -0.00367342844f);
    p = fmaf(p, w,    0.00573950773f);
    p = fmaf(p, w,   -0.0076224613f);
    p = fmaf(p, w,    0.00943887047f);
    p = fmaf(p, w,    1.00167406f);
    p = fmaf(p, w,    2.83297682f);
  }
  return p * x;
}

__device__ __forceinline__ float uniform_from_bits(u32 bits){
  return __uint_as_float((bits >> 9) | 0x3f800000u) - 1.0f;
}

__device__ __forceinline__ float normal_from_bits(u32 bits){
  float u01 = uniform_from_bits(bits);
  const float lo = -0.99999994f;
  float v = fmaf(u01, 2.0f, lo);
  v = fmaxf(lo, v);
  return 1.41421356f * erfinvf_(v);
}

__device__ __forceinline__ float normal_fast_(u32 bits){
  float u01 = uniform_from_bits(bits);
  const float lo = -0.99999994f;
  float v = fmaf(u01, 2.0f, lo);
  v = fmaxf(lo, v);
  return 1.41421356f * erfinv_fast_(v);
}

__device__ __forceinline__ int warp_idx_(int t, int wp, int sh){
  int tps = t + sh;
  int pos = (t >= wp) ? ((tps < Ld - 1) ? tps : (Ld - 1)) : t;
  int neg = ((t >= wp + sh) && (t < Ld + sh)) ? (t - sh) : t;
  return (sh > 0) ? pos : ((sh < 0) ? neg : t);
}

__device__ __forceinline__ u32 pack_bf16_2(float a, float b){
  u32 ua = __float_as_uint(a), ub = __float_as_uint(b);
  u32 ra = (ua + 0x7FFFu + ((ua >> 16) & 1u)) >> 16;
  u32 rb = (ub + 0x7FFFu + ((ub >> 16) & 1u)) >> 16;
  return (ra & 0xFFFFu) | (rb << 16);
}
__device__ __forceinline__ u16 f2bf(float a){
  u32 ua = __float_as_uint(a);
  return (u16)((ua + 0x7FFFu + ((ua >> 16) & 1u)) >> 16);
}
__device__ __forceinline__ float bf2f(u16 v){
  return __uint_as_float(((u32)v) << 16);
}

__device__ __forceinline__ int swz_(int v){
  return ((v >> 2) & 7) ^ ((v & 3) << 1);
}
__device__ __forceinline__ int rev9_(int k){
  return (int)(__brev((u32)k) >> 23);
}

// ---------------------------------------------------------------------------
// k_mlp: validated R12/R13 -- UNCHANGED (mask draws must stay bit-exact).
// ---------------------------------------------------------------------------
__global__ __launch_bounds__(256) void k_mlp(
    const float* __restrict__ w1, const float* __restrict__ b1,
    const float* __restrict__ w2, const float* __restrict__ b2,
    const float* __restrict__ w3, const float* __restrict__ b3,
    const float* __restrict__ wsc, const float* __restrict__ bsc,
    const float* __restrict__ p_scale, const float* __restrict__ p_shift,
    u16* __restrict__ h3b, float* __restrict__ scl,
    int* __restrict__ wp, int* __restrict__ shv,
    u8* __restrict__ fm)
{
  __shared__ float zs[64];
  __shared__ float h1s[128];
  __shared__ float h2s[256];
  __shared__ float hs[256];
  const int bid = blockIdx.x;
  const int n = threadIdx.x;

  // ---- freq-mask row (all 8192 blocks) ----
  {
    int fb = bid >> 5;           // batch row
    int jf = bid & 31;           // feature-pair index
    int fA = jf << 1;
    float s_shift = sigmoidf_(p_shift[0]);
    float s_mix = 1.0f - s_shift;
    float ratio = fminf(s_mix * 0.1f, 0.5f);
    U2 kf = split_key(0u, 42u, 4u);
    int nItr = (n == 0) ? 2 : 1;
    for (int e = 0; e < nItr; ++e){
      int kk = (e == 0) ? n : 256;
      int nk = (512 - kk) & 511;
      u32 ck = (u32)((fb * Ld + kk) * Fd + fA);
      u32 cn = (u32)((fb * Ld + nk) * Fd + fA);
      int k0a = (uniform_from_bits(rb32(kf.a, kf.b, ck))      > ratio) ? 1 : 0;
      int k0b = (uniform_from_bits(rb32(kf.a, kf.b, cn))      > ratio) ? 1 : 0;
      int k1a = (uniform_from_bits(rb32(kf.a, kf.b, ck + 1u)) > ratio) ? 1 : 0;
      int k1b = (uniform_from_bits(rb32(kf.a, kf.b, cn + 1u)) > ratio) ? 1 : 0;
      fm[(size_t)bid * 257 + kk] = (u8)((k0a + k0b) | ((k1a + k1b) << 2));
    }
  }

  if (bid >= 256) return;
  const int b = bid;

  if (n < 64){
    U2 kz = split_key(0u, 42u, 0u);
    zs[n] = normal_from_bits(rb32(kz.a, kz.b, (u32)(b * 64 + n)));
  }
  __syncthreads();

  if (n < 128){
    float acc = b1[n];
    #pragma unroll 8
    for (int k = 0; k < 64; ++k) acc = fmaf(zs[k], w1[k * 128 + n], acc);
    h1s[n] = leakyf_(acc);
  }
  __syncthreads();

  {
    float acc = b2[n];
    #pragma unroll 8
    for (int k = 0; k < 128; ++k) acc = fmaf(h1s[k], w2[k * 256 + n], acc);
    h2s[n] = leakyf_(acc);
  }
  __syncthreads();

  {
    float acc = b3[n];
    #pragma unroll 8
    for (int k = 0; k < 256; ++k) acc = fmaf(h2s[k], w3[k * 256 + n], acc);
    u16 hv = f2bf(leakyf_(acc));
    h3b[b * 256 + n] = hv;
    hs[n] = bf2f(hv);
  }
  __syncthreads();

  if (n < 64){
    float a2 = bsc[n];
    for (int k = 0; k < 256; ++k) a2 = fmaf(hs[k], wsc[k * 64 + n], a2);
    float s_scale = sigmoidf_(p_scale[0]);
    scl[b * 64 + n] = 1.0f + (softplusf_(a2) - 0.5f) * 0.2f * s_scale;
  }

  if (b < 2 && n < 128){
    int bb = b * 128 + n;
    float s_shift = sigmoidf_(p_shift[0]);
    int wsteps = (int)(51.2f * s_shift);
    U2 kwp = split_key(0u, 42u, 2u);
    U2 ksh = split_key(0u, 42u, 3u);
    {
      U2 k1 = split_key(kwp.a, kwp.b, 0u);
      U2 k2 = split_key(kwp.a, kwp.b, 1u);
      u32 hi = rb32(k1.a, k1.b, (u32)bb);
      u32 lo = rb32(k2.a, k2.b, (u32)bb);
      u32 span = (u32)(Ld - 2 * wsteps);
      u32 mult = 65536u % span; mult = (mult * mult) % span;
      u32 off = ((hi % span) * mult + (lo % span)) % span;
      wp[bb] = wsteps + (int)off;
    }
    {
      U2 k1 = split_key(ksh.a, ksh.b, 0u);
      U2 k2 = split_key(ksh.a, ksh.b, 1u);
      u32 hi = rb32(k1.a, k1.b, (u32)bb);
      u32 lo = rb32(k2.a, k2.b, (u32)bb);
      u32 span = (u32)(2 * wsteps + 1);
      u32 mult = 65536u % span; mult = (mult * mult) % span;
      u32 off = ((hi % span) * mult + (lo % span)) % span;
      shv[bb] = -wsteps + (int)off;
    }
  }
}

// ---------------------------------------------------------------------------
// k_gemm: byte-identical to validated R9/R13.
// ---------------------------------------------------------------------------
typedef short short8 __attribute__((ext_vector_type(8)));
typedef float f32x4 __attribute__((ext_vector_type(4)));
union Frag { uint4 u; short8 s; };

__global__ __launch_bounds__(256, 2) void k_gemm(
    const u16* __restrict__ h3b,
    const float* __restrict__ wm, const float* __restrict__ bm,
    const float* __restrict__ wn, const float* __restrict__ bn,
    u32* __restrict__ mn)
{
  __shared__ __align__(16) u32 As [128 * 32];
  __shared__ __align__(16) u32 Bs0[128 * 32];
  __shared__ __align__(16) u32 Bs1[128 * 32];

  const int tid  = threadIdx.x;
  const int lane = tid & 63;
  const int w    = tid >> 6;
  const int q    = lane >> 4;
  const int lo   = lane & 15;
  const int nt0  = blockIdx.x << 7;
  const int b0   = blockIdx.y << 7;
  const int wr   = (w >> 1) << 6;
  const int wc   = (w & 1) << 6;

  const int p  = lane >> 3;
  const int c8 = lane & 7;
  const int nb = (w << 5) + (p << 2);

  f32x4 accm[4][4], accn[4][4];
  #pragma unroll
  for (int i = 0; i < 4; ++i)
    #pragma unroll
    for (int j = 0; j < 4; ++j){ accm[i][j] = (f32x4)0.0f; accn[i][j] = (f32x4)0.0f; }

  for (int kc = 0; kc < 256; kc += 64){
    if (kc) __syncthreads();
    #pragma unroll
    for (int j = 0; j < 4; ++j){
      int idx  = j * 256 + tid;
      int row  = idx >> 3;
      int slot = idx & 7;
      int g    = slot ^ swz_(row);
      uint4 v  = *(const uint4*)(h3b + (size_t)(b0 + row) * 256 + kc + g * 8);
      *(uint4*)&As[row * 32 + slot * 4] = v;
    }
    #pragma unroll
    for (int cp = 0; cp < 4; ++cp){
      int c = cp * 8 + c8;
      size_t gb = (size_t)(kc + 2 * c) * Nd + nt0 + nb;
      float4 m0 = *(const float4*)(wm + gb);
      float4 m1 = *(const float4*)(wm + gb + Nd);
      float4 v0 = *(const float4*)(wn + gb);
      float4 v1 = *(const float4*)(wn + gb + Nd);
      int g = c >> 2, cl = c & 3;
      #pragma unroll
      for (int s = 0; s < 4; ++s){
        int n = nb + s;
        int addr = n * 32 + (g ^ swz_(n)) * 4 + cl;
        float a0 = (s == 0) ? m0.x : (s == 1) ? m0.y : (s == 2) ? m0.z : m0.w;
        float a1 = (s == 0) ? m1.x : (s == 1) ? m1.y : (s == 2) ? m1.z : m1.w;
        float b0f = (s == 0) ? v0.x : (s == 1) ? v0.y : (s == 2) ? v0.z : v0.w;
        float b1f = (s == 0) ? v1.x : (s == 1) ? v1.y : (s == 2) ? v1.z : v1.w;
        Bs0[addr] = pack_bf16_2(a0, a1);
        Bs1[addr] = pack_bf16_2(b0f, b1f);
      }
    }
    __syncthreads();

    #pragma unroll
    for (int u = 0; u < 2; ++u){
      int G = u * 4 + q;
      Frag af[4], bfm[4], bfn[4];
      #pragma unroll
      for (int mt = 0; mt < 4; ++mt){
        int row = wr + mt * 16 + lo;
        af[mt].u = *(const uint4*)&As[row * 32 + (G ^ swz_(row)) * 4];
      }
      #pragma unroll
      for (int nt = 0; nt < 4; ++nt){
        int n = wc + nt * 16 + lo;
        int ad = n * 32 + (G ^ swz_(n)) * 4;
        bfm[nt].u = *(const uint4*)&Bs0[ad];
        bfn[nt].u = *(const uint4*)&Bs1[ad];
      }
      #pragma unroll
      for (int mt = 0; mt < 4; ++mt){
        #pragma unroll
        for (int nt = 0; nt < 4; ++nt){
          accm[mt][nt] = __builtin_amdgcn_mfma_f32_16x16x32_bf16(af[mt].s, bfm[nt].s, accm[mt][nt], 0, 0, 0);
          accn[mt][nt] = __builtin_amdgcn_mfma_f32_16x16x32_bf16(af[mt].s, bfn[nt].s, accn[mt][nt], 0, 0, 0);
        }
      }
    }
  }

  #pragma unroll
  for (int nt = 0; nt < 4; ++nt){
    int n = nt0 + wc + nt * 16 + lo;
    float bmv = bm[n];
    float bnv = bn[n];
    #pragma unroll
    for (int mt = 0; mt < 4; ++mt){
      #pragma unroll
      for (int r = 0; r < 4; ++r){
        int b = b0 + wr + mt * 16 + q * 4 + r;
        size_t o = (size_t)b * Nd + n;
        mn[o] = pack_bf16_2(accm[mt][nt][r] + bmv, accn[mt][nt][r] + bnv);
      }
    }
  }
}

// ---------------------------------------------------------------------------
// k_noise: R13 structure; softplus/normal switched to native-exp/log fast
// paths (same polynomial, same branch, same counters).
// ---------------------------------------------------------------------------
__global__ __launch_bounds__(256) void k_noise(u32* __restrict__ mn,
                                               const float* __restrict__ p_noise){
  int gid = blockIdx.x * 256 + threadIdx.x;
  u32 base = (u32)gid * 8u;
  float s_noise = sigmoidf_(p_noise[0]);
  float sc = s_noise * 0.05f;
  U2 knk = split_key(0u, 42u, 1u);

  uint4 v0 = *(const uint4*)(mn + base);
  uint4 v1 = *(const uint4*)(mn + base + 4);
  u32 wds[8] = {v0.x, v0.y, v0.z, v0.w, v1.x, v1.y, v1.z, v1.w};
  #pragma unroll
  for (int h = 0; h < 8; ++h){
    u16 logit = (u16)(wds[h] >> 16);
    float nm = softplus_fast_(bf2f(logit));
    float nz = normal_fast_(rb32(knk.a, knk.b, base + (u32)h));
    wds[h] = (wds[h] & 0xFFFFu) | ((u32)f2bf(nz * nm * sc) << 16);
  }
  *(uint4*)(mn + base)     = make_uint4(wds[0], wds[1], wds[2], wds[3]);
  *(uint4*)(mn + base + 4) = make_uint4(wds[4], wds[5], wds[6], wds[7]);
}

// ---------------------------------------------------------------------------
// k_faug: R13 geometry (16-feature tile, fm mask-byte repack); per-element
// mask sigmoid switched to native-exp fast path.
// ---------------------------------------------------------------------------
#define PITCH 529

__device__ __forceinline__ int lphys(int t){ return t + (t >> 5); }

__global__ __launch_bounds__(256, 4) void k_faug(
    const float* __restrict__ x,
    u32* mn,
    const float* __restrict__ scl,
    const int* __restrict__ wp, const int* __restrict__ shv,
    const u8* __restrict__ fm,
    const float* __restrict__ p_mask, const float* __restrict__ p_shift)
{
  __shared__ float SR[8 * PITCH];
  __shared__ float SI[8 * PITCH];
  __shared__ float2 tw[256];

  const int tid = threadIdx.x;
  const int b   = blockIdx.x >> 2;
  const int f0  = (blockIdx.x & 3) << 4;

  float s_mask  = sigmoidf_(p_mask[0]);
  float s_shift = sigmoidf_(p_shift[0]);
  float s_mix   = 1.0f - s_shift;
  float wa = 1.0f - s_mix - s_shift;
  wa = fminf(fmaxf(wa, 0.1f), 0.8f);
  float wb = s_mix * 0.5f;
  float wc = s_shift * 0.5f;
  float tot = wa + wb + wc;
  wa /= tot; wb /= tot; wc /= tot;
  bool pass = (s_mix < 0.01f);

  const int wpb = wp[b];
  const int shb = shv[b];

  {
    float ang = -6.283185307179586f * ((float)tid / 512.0f);
    tw[tid] = make_float2(cosf(ang), sinf(ang));
  }

  // ---- stage in + pack pairs ----
  const float* xb = x + (size_t)b * Nd;
  #pragma unroll
  for (int s = 0; s < 8; ++s){
    int qq = (s << 8) + tid;        // float4 id, 0..2047
    int t  = qq >> 2;
    int f4 = qq & 3;
    float4 v = *(const float4*)(xb + t * 64 + f0 + (f4 << 2));
    int j = f4 << 1;
    int pt = lphys(t);
    SR[j * PITCH + pt]       = v.x;  SI[j * PITCH + pt]       = v.y;
    SR[(j + 1) * PITCH + pt] = v.z;  SI[(j + 1) * PITCH + pt] = v.w;
  }
  __syncthreads();

  // ---- forward DIF (natural in -> bitrev out) ----
  for (int s = 9; s >= 1; --s){
    int half = 1 << (s - 1);
    #pragma unroll
    for (int it = 0; it < 8; ++it){
      int j  = it;
      int bi = tid;
      int pos = bi & (half - 1);
      int g = bi >> (s - 1);
      int i1 = (g << s) + pos;
      int i2 = i1 + half;
      int a1 = j * PITCH + lphys(i1);
      int a2 = j * PITCH + lphys(i2);
      float ur = SR[a1], ui = SI[a1];
      float vr = SR[a2], vi = SI[a2];
      SR[a1] = ur + vr; SI[a1] = ui + vi;
      float dr = ur - vr, di = ui - vi;
      float2 w = tw[pos << (9 - s)];
      SR[a2] = dr * w.x - di * w.y;
      SI[a2] = dr * w.y + di * w.x;
    }
    __syncthreads();
  }

  // ---- masked Hermitian repack (masks from fm, decode exact) ----
  {
    const u8* fmb = fm + ((size_t)((b << 5) + (f0 >> 1))) * 257;
    #pragma unroll
    for (int it = 0; it < 8; ++it){
      int j = it;
      int k = tid;
      int nItr = (k == 0) ? 2 : 1;
      for (int e = 0; e < nItr; ++e){
        int kk = (e == 0) ? k : 256;
        int nk = (512 - kk) & 511;
        int pk = rev9_(kk), pn = rev9_(nk);
        int ak = j * PITCH + lphys(pk);
        int an = j * PITCH + lphys(pn);
        float zkr = SR[ak], zki = SI[ak];
        float znr = SR[an], zni = SI[an];
        float X0r = 0.5f * (zkr + znr), X0i = 0.5f * (zki - zni);
        float X1r = 0.5f * (zki + zni), X1i = 0.5f * (znr - zkr);
        u8 mq = fmb[j * 257 + kk];
        float m0 = 0.5f * (float)(mq & 3);
        float m1 = 0.5f * (float)(mq >> 2);
        SR[ak] = m0 * X0r - m1 * X1i;
        SI[ak] = m0 * X0i + m1 * X1r;
        SR[an] = m0 * X0r + m1 * X1i;
        SI[an] = m1 * X1r - m0 * X0i;
      }
    }
  }
  __syncthreads();

  // ---- inverse DIT (bitrev in -> natural out) ----
  for (int s = 1; s <= 9; ++s){
    int half = 1 << (s - 1);
    #pragma unroll
    for (int it = 0; it < 8; ++it){
      int j  = it;
      int bi = tid;
      int pos = bi & (half - 1);
      int g = bi >> (s - 1);
      int i1 = (g << s) + pos;
      int i2 = i1 + half;
      int a1 = j * PITCH + lphys(i1);
      int a2 = j * PITCH + lphys(i2);
      float2 w = tw[pos << (9 - s)];
      float vr = SR[a2], vi = SI[a2];
      float tx_ = vr * w.x + vi * w.y;    // v * conj(w)
      float ty_ = vi * w.x - vr * w.y;
      float ur = SR[a1], ui = SI[a1];
      SR[a1] = ur + tx_; SI[a1] = ui + ty_;
      SR[a2] = ur - tx_; SI[a2] = ui - ty_;
    }
    __syncthreads();
  }

  // ---- fused augmentation epilogue (packed in-place mn read/write) ----
  const float inv512 = 1.0f / 512.0f;
  u32* mnb = mn + (size_t)b * Nd;
  #pragma unroll
  for (int s = 0; s < 8; ++s){
    int qq = (s << 8) + tid;
    int t  = qq >> 2;
    int f4 = qq & 3;
    int f  = f0 + (f4 << 2);
    int j  = f4 << 1;
    int pt = lphys(t);
    int nidx = t * 64 + f;
    float4 xv = *(const float4*)(xb + nidx);
    int wi = warp_idx_(t, wpb, shb);
    float4 wv = *(const float4*)(xb + wi * 64 + f);
    float4 sc = *(const float4*)(scl + b * 64 + f);
    uint4 w4 = *(const uint4*)(mnb + nidx);
    float fr[4];
    fr[0] = SR[j * PITCH + pt] * inv512;
    fr[1] = SI[j * PITCH + pt] * inv512;
    fr[2] = SR[(j + 1) * PITCH + pt] * inv512;
    fr[3] = SI[(j + 1) * PITCH + pt] * inv512;
    const float xvv[4] = {xv.x, xv.y, xv.z, xv.w};
    const float wvv[4] = {wv.x, wv.y, wv.z, wv.w};
    const float scv[4] = {sc.x, sc.y, sc.z, sc.w};
    const u32 wdv[4] = {w4.x, w4.y, w4.z, w4.w};
    float o[4];
    #pragma unroll
    for (int c = 0; c < 4; ++c){
      float maskv = sigmoid_fast_(bf2f((u16)(wdv[c] & 0xFFFFu)));
      maskv = 1.0f - (1.0f - maskv) * s_mask * 0.3f;
      float noise = bf2f((u16)(wdv[c] >> 16));
      float fq = pass ? xvv[c] : fr[c];
      float aug = fmaf(xvv[c] * maskv, scv[c], noise);
      o[c] = aug * wa + fq * wb + wvv[c] * wc;
    }
    *(float4*)(mnb + nidx) = make_float4(o[0], o[1], o[2], o[3]);
  }
}

// ---------------------------------------------------------------------------
extern "C" void kernel_launch(void* const* d_in, const int* in_sizes, int n_in,
                              void* d_out, int out_size, void* d_ws, size_t ws_size,
                              hipStream_t stream)
{
  (void)in_sizes; (void)n_in; (void)out_size; (void)ws_size;
  const float* x   = (const float*)d_in[0];
  const float* w1  = (const float*)d_in[2];
  const float* b1  = (const float*)d_in[3];
  const float* w2  = (const float*)d_in[4];
  const float* b2  = (const float*)d_in[5];
  const float* w3  = (const float*)d_in[6];
  const float* b3  = (const float*)d_in[7];
  const float* wm  = (const float*)d_in[8];
  const float* bm  = (const float*)d_in[9];
  const float* wn  = (const float*)d_in[10];
  const float* bn  = (const float*)d_in[11];
  const float* wsc = (const float*)d_in[12];
  const float* bsc = (const float*)d_in[13];
  const float* pm  = (const float*)d_in[14];
  const float* pn  = (const float*)d_in[15];
  const float* psh = (const float*)d_in[16];
  const float* psc = (const float*)d_in[17];
  char* ws = (char*)d_ws;

  // ws: wp 1KB | shv 1KB+pad | h3b 128KB | scl 64KB | fm 2.06MB  (~2.3MB)
  int*   wp   = (int*)(ws + 0);
  int*   shv  = (int*)(ws + 1024);
  u16*   h3b  = (u16*)(ws + 4096);
  float* scl  = (float*)(ws + 4096 + 131072);
  u8*    fm   = (u8*) (ws + 4096 + 131072 + 65536);
  u32*   mn   = (u32*)d_out;

  k_mlp  <<<dim3(8192),    dim3(256), 0, stream>>>(w1, b1, w2, b2, w3, b3,
                                                   wsc, bsc, psc, psh,
                                                   h3b, scl, wp, shv, fm);
  k_gemm <<<dim3(256, 2),  dim3(256), 0, stream>>>(h3b, wm, bm, wn, bn, mn);
  k_noise<<<dim3(4096),    dim3(256), 0, stream>>>(mn, pn);
  k_faug <<<dim3(1024),    dim3(256), 0, stream>>>(x, mn, scl, wp, shv, fm,
                                                   pm, psh);
}

// Round 11
// 262.634 us; speedup vs baseline: 2.0687x; 1.0462x over previous
//
#include <hip/hip_runtime.h>
#include <cstdint>
#include <cstddef>

// ============================================================================
// MaskGenerator R15: fuse k_noise INTO k_faug's epilogue. R14 counters show
// k_faug is latency/LDS-bound (VALUBusy 28.5% -- 71% issue idle) while
// k_noise is pure VALU (~100% busy, ~25-30us): the noise math can hide in
// k_faug's idle issue slots. Unlike R7's failed fusion (register-fat GEMM ->
// spills), k_faug is 52 VGPR with headroom. Noise path is bit-identical to
// R14: same fast-path softplus/erfinv, same counters (b*Nd+nidx+c), same
// DOUBLE bf16 rounding (noise = bf2f(f2bf(nz*nm*sc))). mn high half now
// carries the logN logit straight from k_gemm. Chain 4 -> 3 kernels; mn's
// 50MB k_noise round-trip eliminated. k_mlp / k_gemm byte-identical R14.
// ============================================================================

typedef unsigned int u32;
typedef unsigned short u16;
typedef unsigned char u8;

#define Bd 256
#define Ld 512
#define Fd 64
#define Nd 32768            // Ld*Fd

struct U2 { u32 a, b; };

__device__ __forceinline__ u32 rotl32(u32 x, int r){ return (x << r) | (x >> (32 - r)); }

__device__ __forceinline__ U2 tf2x32(u32 k0, u32 k1, u32 x0, u32 x1){
  u32 ks2 = k0 ^ k1 ^ 0x1BD11BDAu;
  x0 += k0; x1 += k1;
#define TFR4(r0,r1,r2,r3) \
  x0 += x1; x1 = rotl32(x1, r0); x1 ^= x0; \
  x0 += x1; x1 = rotl32(x1, r1); x1 ^= x0; \
  x0 += x1; x1 = rotl32(x1, r2); x1 ^= x0; \
  x0 += x1; x1 = rotl32(x1, r3); x1 ^= x0;
  TFR4(13,15,26,6)  x0 += k1;  x1 += ks2 + 1u;
  TFR4(17,29,16,24) x0 += ks2; x1 += k0 + 2u;
  TFR4(13,15,26,6)  x0 += k0;  x1 += k1 + 3u;
  TFR4(17,29,16,24) x0 += k1;  x1 += ks2 + 4u;
  TFR4(13,15,26,6)  x0 += ks2; x1 += k0 + 5u;
#undef TFR4
  U2 r; r.a = x0; r.b = x1; return r;
}

__device__ __forceinline__ u32 rb32(u32 k0, u32 k1, u32 i){
  U2 r = tf2x32(k0, k1, 0u, i);
  return r.a ^ r.b;
}

__device__ __forceinline__ U2 split_key(u32 k0, u32 k1, u32 j){
  return tf2x32(k0, k1, 0u, j);
}

__device__ __forceinline__ float sigmoidf_(float x){ return 1.0f / (1.0f + expf(-x)); }
__device__ __forceinline__ float softplusf_(float x){ return fmaxf(x, 0.0f) + log1pf(expf(-fabsf(x))); }
__device__ __forceinline__ float leakyf_(float x){ return (x > 0.0f) ? x : 0.2f * x; }

// ---- fast (native v_exp_f32 / v_log_f32) variants (validated R14)
__device__ __forceinline__ float sigmoid_fast_(float x){
  return 1.0f / (1.0f + __expf(-x));
}
__device__ __forceinline__ float softplus_fast_(float x){
  return fmaxf(x, 0.0f) + __logf(1.0f + __expf(-fabsf(x)));
}

__device__ __forceinline__ float erfinvf_(float x){
  float w = -log1pf(-x * x);
  float p;
  if (w < 5.0f){
    w -= 2.5f;
    p =               2.81022636e-08f;
    p = fmaf(p, w,    3.43273939e-07f);
    p = fmaf(p, w,   -3.5233877e-06f);
    p = fmaf(p, w,   -4.39150654e-06f);
    p = fmaf(p, w,    0.00021858087f);
    p = fmaf(p, w,   -0.00125372503f);
    p = fmaf(p, w,   -0.00417768164f);
    p = fmaf(p, w,    0.246640727f);
    p = fmaf(p, w,    1.50140941f);
  } else {
    w = sqrtf(w) - 3.0f;
    p =              -0.000200214257f;
    p = fmaf(p, w,    0.000100950558f);
    p = fmaf(p, w,    0.00134934322f);
    p = fmaf(p, w,   -0.00367342844f);
    p = fmaf(p, w,    0.00573950773f);
    p = fmaf(p, w,   -0.0076224613f);
    p = fmaf(p, w,    0.00943887047f);
    p = fmaf(p, w,    1.00167406f);
    p = fmaf(p, w,    2.83297682f);
  }
  return p * x;
}

__device__ __forceinline__ float erfinv_fast_(float x){
  float t = x * x;
  float w = -__logf(1.0f - t);
  float p;
  if (w < 5.0f){
    w -= 2.5f;
    p =               2.81022636e-08f;
    p = fmaf(p, w,    3.43273939e-07f);
    p = fmaf(p, w,   -3.5233877e-06f);
    p = fmaf(p, w,   -4.39150654e-06f);
    p = fmaf(p, w,    0.00021858087f);
    p = fmaf(p, w,   -0.00125372503f);
    p = fmaf(p, w,   -0.00417768164f);
    p = fmaf(p, w,    0.246640727f);
    p = fmaf(p, w,    1.50140941f);
  } else {
    w = sqrtf(w) - 3.0f;
    p =              -0.000200214257f;
    p = fmaf(p, w,    0.000100950558f);
    p = fmaf(p, w,    0.00134934322f);
    p = fmaf(p, w,   -0.00367342844f);
    p = fmaf(p, w,    0.00573950773f);
    p = fmaf(p, w,   -0.0076224613f);
    p = fmaf(p, w,    0.00943887047f);
    p = fmaf(p, w,    1.00167406f);
    p = fmaf(p, w,    2.83297682f);
  }
  return p * x;
}

__device__ __forceinline__ float uniform_from_bits(u32 bits){
  return __uint_as_float((bits >> 9) | 0x3f800000u) - 1.0f;
}

__device__ __forceinline__ float normal_from_bits(u32 bits){
  float u01 = uniform_from_bits(bits);
  const float lo = -0.99999994f;
  float v = fmaf(u01, 2.0f, lo);
  v = fmaxf(lo, v);
  return 1.41421356f * erfinvf_(v);
}

__device__ __forceinline__ float normal_fast_(u32 bits){
  float u01 = uniform_from_bits(bits);
  const float lo = -0.99999994f;
  float v = fmaf(u01, 2.0f, lo);
  v = fmaxf(lo, v);
  return 1.41421356f * erfinv_fast_(v);
}

__device__ __forceinline__ int warp_idx_(int t, int wp, int sh){
  int tps = t + sh;
  int pos = (t >= wp) ? ((tps < Ld - 1) ? tps : (Ld - 1)) : t;
  int neg = ((t >= wp + sh) && (t < Ld + sh)) ? (t - sh) : t;
  return (sh > 0) ? pos : ((sh < 0) ? neg : t);
}

__device__ __forceinline__ u32 pack_bf16_2(float a, float b){
  u32 ua = __float_as_uint(a), ub = __float_as_uint(b);
  u32 ra = (ua + 0x7FFFu + ((ua >> 16) & 1u)) >> 16;
  u32 rb = (ub + 0x7FFFu + ((ub >> 16) & 1u)) >> 16;
  return (ra & 0xFFFFu) | (rb << 16);
}
__device__ __forceinline__ u16 f2bf(float a){
  u32 ua = __float_as_uint(a);
  return (u16)((ua + 0x7FFFu + ((ua >> 16) & 1u)) >> 16);
}
__device__ __forceinline__ float bf2f(u16 v){
  return __uint_as_float(((u32)v) << 16);
}

__device__ __forceinline__ int swz_(int v){
  return ((v >> 2) & 7) ^ ((v & 3) << 1);
}
__device__ __forceinline__ int rev9_(int k){
  return (int)(__brev((u32)k) >> 23);
}

// ---------------------------------------------------------------------------
// k_mlp: validated R12/R13/R14 -- UNCHANGED (mask draws stay bit-exact).
// ---------------------------------------------------------------------------
__global__ __launch_bounds__(256) void k_mlp(
    const float* __restrict__ w1, const float* __restrict__ b1,
    const float* __restrict__ w2, const float* __restrict__ b2,
    const float* __restrict__ w3, const float* __restrict__ b3,
    const float* __restrict__ wsc, const float* __restrict__ bsc,
    const float* __restrict__ p_scale, const float* __restrict__ p_shift,
    u16* __restrict__ h3b, float* __restrict__ scl,
    int* __restrict__ wp, int* __restrict__ shv,
    u8* __restrict__ fm)
{
  __shared__ float zs[64];
  __shared__ float h1s[128];
  __shared__ float h2s[256];
  __shared__ float hs[256];
  const int bid = blockIdx.x;
  const int n = threadIdx.x;

  // ---- freq-mask row (all 8192 blocks) ----
  {
    int fb = bid >> 5;           // batch row
    int jf = bid & 31;           // feature-pair index
    int fA = jf << 1;
    float s_shift = sigmoidf_(p_shift[0]);
    float s_mix = 1.0f - s_shift;
    float ratio = fminf(s_mix * 0.1f, 0.5f);
    U2 kf = split_key(0u, 42u, 4u);
    int nItr = (n == 0) ? 2 : 1;
    for (int e = 0; e < nItr; ++e){
      int kk = (e == 0) ? n : 256;
      int nk = (512 - kk) & 511;
      u32 ck = (u32)((fb * Ld + kk) * Fd + fA);
      u32 cn = (u32)((fb * Ld + nk) * Fd + fA);
      int k0a = (uniform_from_bits(rb32(kf.a, kf.b, ck))      > ratio) ? 1 : 0;
      int k0b = (uniform_from_bits(rb32(kf.a, kf.b, cn))      > ratio) ? 1 : 0;
      int k1a = (uniform_from_bits(rb32(kf.a, kf.b, ck + 1u)) > ratio) ? 1 : 0;
      int k1b = (uniform_from_bits(rb32(kf.a, kf.b, cn + 1u)) > ratio) ? 1 : 0;
      fm[(size_t)bid * 257 + kk] = (u8)((k0a + k0b) | ((k1a + k1b) << 2));
    }
  }

  if (bid >= 256) return;
  const int b = bid;

  if (n < 64){
    U2 kz = split_key(0u, 42u, 0u);
    zs[n] = normal_from_bits(rb32(kz.a, kz.b, (u32)(b * 64 + n)));
  }
  __syncthreads();

  if (n < 128){
    float acc = b1[n];
    #pragma unroll 8
    for (int k = 0; k < 64; ++k) acc = fmaf(zs[k], w1[k * 128 + n], acc);
    h1s[n] = leakyf_(acc);
  }
  __syncthreads();

  {
    float acc = b2[n];
    #pragma unroll 8
    for (int k = 0; k < 128; ++k) acc = fmaf(h1s[k], w2[k * 256 + n], acc);
    h2s[n] = leakyf_(acc);
  }
  __syncthreads();

  {
    float acc = b3[n];
    #pragma unroll 8
    for (int k = 0; k < 256; ++k) acc = fmaf(h2s[k], w3[k * 256 + n], acc);
    u16 hv = f2bf(leakyf_(acc));
    h3b[b * 256 + n] = hv;
    hs[n] = bf2f(hv);
  }
  __syncthreads();

  if (n < 64){
    float a2 = bsc[n];
    for (int k = 0; k < 256; ++k) a2 = fmaf(hs[k], wsc[k * 64 + n], a2);
    float s_scale = sigmoidf_(p_scale[0]);
    scl[b * 64 + n] = 1.0f + (softplusf_(a2) - 0.5f) * 0.2f * s_scale;
  }

  if (b < 2 && n < 128){
    int bb = b * 128 + n;
    float s_shift = sigmoidf_(p_shift[0]);
    int wsteps = (int)(51.2f * s_shift);
    U2 kwp = split_key(0u, 42u, 2u);
    U2 ksh = split_key(0u, 42u, 3u);
    {
      U2 k1 = split_key(kwp.a, kwp.b, 0u);
      U2 k2 = split_key(kwp.a, kwp.b, 1u);
      u32 hi = rb32(k1.a, k1.b, (u32)bb);
      u32 lo = rb32(k2.a, k2.b, (u32)bb);
      u32 span = (u32)(Ld - 2 * wsteps);
      u32 mult = 65536u % span; mult = (mult * mult) % span;
      u32 off = ((hi % span) * mult + (lo % span)) % span;
      wp[bb] = wsteps + (int)off;
    }
    {
      U2 k1 = split_key(ksh.a, ksh.b, 0u);
      U2 k2 = split_key(ksh.a, ksh.b, 1u);
      u32 hi = rb32(k1.a, k1.b, (u32)bb);
      u32 lo = rb32(k2.a, k2.b, (u32)bb);
      u32 span = (u32)(2 * wsteps + 1);
      u32 mult = 65536u % span; mult = (mult * mult) % span;
      u32 off = ((hi % span) * mult + (lo % span)) % span;
      shv[bb] = -wsteps + (int)off;
    }
  }
}

// ---------------------------------------------------------------------------
// k_gemm: byte-identical to validated R9/R13/R14.
// ---------------------------------------------------------------------------
typedef short short8 __attribute__((ext_vector_type(8)));
typedef float f32x4 __attribute__((ext_vector_type(4)));
union Frag { uint4 u; short8 s; };

__global__ __launch_bounds__(256, 2) void k_gemm(
    const u16* __restrict__ h3b,
    const float* __restrict__ wm, const float* __restrict__ bm,
    const float* __restrict__ wn, const float* __restrict__ bn,
    u32* __restrict__ mn)
{
  __shared__ __align__(16) u32 As [128 * 32];
  __shared__ __align__(16) u32 Bs0[128 * 32];
  __shared__ __align__(16) u32 Bs1[128 * 32];

  const int tid  = threadIdx.x;
  const int lane = tid & 63;
  const int w    = tid >> 6;
  const int q    = lane >> 4;
  const int lo   = lane & 15;
  const int nt0  = blockIdx.x << 7;
  const int b0   = blockIdx.y << 7;
  const int wr   = (w >> 1) << 6;
  const int wc   = (w & 1) << 6;

  const int p  = lane >> 3;
  const int c8 = lane & 7;
  const int nb = (w << 5) + (p << 2);

  f32x4 accm[4][4], accn[4][4];
  #pragma unroll
  for (int i = 0; i < 4; ++i)
    #pragma unroll
    for (int j = 0; j < 4; ++j){ accm[i][j] = (f32x4)0.0f; accn[i][j] = (f32x4)0.0f; }

  for (int kc = 0; kc < 256; kc += 64){
    if (kc) __syncthreads();
    #pragma unroll
    for (int j = 0; j < 4; ++j){
      int idx  = j * 256 + tid;
      int row  = idx >> 3;
      int slot = idx & 7;
      int g    = slot ^ swz_(row);
      uint4 v  = *(const uint4*)(h3b + (size_t)(b0 + row) * 256 + kc + g * 8);
      *(uint4*)&As[row * 32 + slot * 4] = v;
    }
    #pragma unroll
    for (int cp = 0; cp < 4; ++cp){
      int c = cp * 8 + c8;
      size_t gb = (size_t)(kc + 2 * c) * Nd + nt0 + nb;
      float4 m0 = *(const float4*)(wm + gb);
      float4 m1 = *(const float4*)(wm + gb + Nd);
      float4 v0 = *(const float4*)(wn + gb);
      float4 v1 = *(const float4*)(wn + gb + Nd);
      int g = c >> 2, cl = c & 3;
      #pragma unroll
      for (int s = 0; s < 4; ++s){
        int n = nb + s;
        int addr = n * 32 + (g ^ swz_(n)) * 4 + cl;
        float a0 = (s == 0) ? m0.x : (s == 1) ? m0.y : (s == 2) ? m0.z : m0.w;
        float a1 = (s == 0) ? m1.x : (s == 1) ? m1.y : (s == 2) ? m1.z : m1.w;
        float b0f = (s == 0) ? v0.x : (s == 1) ? v0.y : (s == 2) ? v0.z : v0.w;
        float b1f = (s == 0) ? v1.x : (s == 1) ? v1.y : (s == 2) ? v1.z : v1.w;
        Bs0[addr] = pack_bf16_2(a0, a1);
        Bs1[addr] = pack_bf16_2(b0f, b1f);
      }
    }
    __syncthreads();

    #pragma unroll
    for (int u = 0; u < 2; ++u){
      int G = u * 4 + q;
      Frag af[4], bfm[4], bfn[4];
      #pragma unroll
      for (int mt = 0; mt < 4; ++mt){
        int row = wr + mt * 16 + lo;
        af[mt].u = *(const uint4*)&As[row * 32 + (G ^ swz_(row)) * 4];
      }
      #pragma unroll
      for (int nt = 0; nt < 4; ++nt){
        int n = wc + nt * 16 + lo;
        int ad = n * 32 + (G ^ swz_(n)) * 4;
        bfm[nt].u = *(const uint4*)&Bs0[ad];
        bfn[nt].u = *(const uint4*)&Bs1[ad];
      }
      #pragma unroll
      for (int mt = 0; mt < 4; ++mt){
        #pragma unroll
        for (int nt = 0; nt < 4; ++nt){
          accm[mt][nt] = __builtin_amdgcn_mfma_f32_16x16x32_bf16(af[mt].s, bfm[nt].s, accm[mt][nt], 0, 0, 0);
          accn[mt][nt] = __builtin_amdgcn_mfma_f32_16x16x32_bf16(af[mt].s, bfn[nt].s, accn[mt][nt], 0, 0, 0);
        }
      }
    }
  }

  #pragma unroll
  for (int nt = 0; nt < 4; ++nt){
    int n = nt0 + wc + nt * 16 + lo;
    float bmv = bm[n];
    float bnv = bn[n];
    #pragma unroll
    for (int mt = 0; mt < 4; ++mt){
      #pragma unroll
      for (int r = 0; r < 4; ++r){
        int b = b0 + wr + mt * 16 + q * 4 + r;
        size_t o = (size_t)b * Nd + n;
        mn[o] = pack_bf16_2(accm[mt][nt][r] + bmv, accn[mt][nt][r] + bnv);
      }
    }
  }
}

// ---------------------------------------------------------------------------
// k_faug: R14 geometry + fused noise in the epilogue. mn high half = logN
// logit (straight from k_gemm); noise computed inline with the exact R14
// fast-path math AND double bf16 rounding -> bit-identical output.
// ---------------------------------------------------------------------------
#define PITCH 529

__device__ __forceinline__ int lphys(int t){ return t + (t >> 5); }

__global__ __launch_bounds__(256, 4) void k_faug(
    const float* __restrict__ x,
    u32* mn,
    const float* __restrict__ scl,
    const int* __restrict__ wp, const int* __restrict__ shv,
    const u8* __restrict__ fm,
    const float* __restrict__ p_mask, const float* __restrict__ p_noise,
    const float* __restrict__ p_shift)
{
  __shared__ float SR[8 * PITCH];
  __shared__ float SI[8 * PITCH];
  __shared__ float2 tw[256];

  const int tid = threadIdx.x;
  const int b   = blockIdx.x >> 2;
  const int f0  = (blockIdx.x & 3) << 4;

  float s_mask  = sigmoidf_(p_mask[0]);
  float s_shift = sigmoidf_(p_shift[0]);
  float s_mix   = 1.0f - s_shift;
  float wa = 1.0f - s_mix - s_shift;
  wa = fminf(fmaxf(wa, 0.1f), 0.8f);
  float wb = s_mix * 0.5f;
  float wc = s_shift * 0.5f;
  float tot = wa + wb + wc;
  wa /= tot; wb /= tot; wc /= tot;
  bool pass = (s_mix < 0.01f);

  const float scn = sigmoidf_(p_noise[0]) * 0.05f;
  U2 knk = split_key(0u, 42u, 1u);

  const int wpb = wp[b];
  const int shb = shv[b];

  {
    float ang = -6.283185307179586f * ((float)tid / 512.0f);
    tw[tid] = make_float2(cosf(ang), sinf(ang));
  }

  // ---- stage in + pack pairs ----
  const float* xb = x + (size_t)b * Nd;
  #pragma unroll
  for (int s = 0; s < 8; ++s){
    int qq = (s << 8) + tid;        // float4 id, 0..2047
    int t  = qq >> 2;
    int f4 = qq & 3;
    float4 v = *(const float4*)(xb + t * 64 + f0 + (f4 << 2));
    int j = f4 << 1;
    int pt = lphys(t);
    SR[j * PITCH + pt]       = v.x;  SI[j * PITCH + pt]       = v.y;
    SR[(j + 1) * PITCH + pt] = v.z;  SI[(j + 1) * PITCH + pt] = v.w;
  }
  __syncthreads();

  // ---- forward DIF (natural in -> bitrev out) ----
  for (int s = 9; s >= 1; --s){
    int half = 1 << (s - 1);
    #pragma unroll
    for (int it = 0; it < 8; ++it){
      int j  = it;
      int bi = tid;
      int pos = bi & (half - 1);
      int g = bi >> (s - 1);
      int i1 = (g << s) + pos;
      int i2 = i1 + half;
      int a1 = j * PITCH + lphys(i1);
      int a2 = j * PITCH + lphys(i2);
      float ur = SR[a1], ui = SI[a1];
      float vr = SR[a2], vi = SI[a2];
      SR[a1] = ur + vr; SI[a1] = ui + vi;
      float dr = ur - vr, di = ui - vi;
      float2 w = tw[pos << (9 - s)];
      SR[a2] = dr * w.x - di * w.y;
      SI[a2] = dr * w.y + di * w.x;
    }
    __syncthreads();
  }

  // ---- masked Hermitian repack (masks from fm, decode exact) ----
  {
    const u8* fmb = fm + ((size_t)((b << 5) + (f0 >> 1))) * 257;
    #pragma unroll
    for (int it = 0; it < 8; ++it){
      int j = it;
      int k = tid;
      int nItr = (k == 0) ? 2 : 1;
      for (int e = 0; e < nItr; ++e){
        int kk = (e == 0) ? k : 256;
        int nk = (512 - kk) & 511;
        int pk = rev9_(kk), pn = rev9_(nk);
        int ak = j * PITCH + lphys(pk);
        int an = j * PITCH + lphys(pn);
        float zkr = SR[ak], zki = SI[ak];
        float znr = SR[an], zni = SI[an];
        float X0r = 0.5f * (zkr + znr), X0i = 0.5f * (zki - zni);
        float X1r = 0.5f * (zki + zni), X1i = 0.5f * (znr - zkr);
        u8 mq = fmb[j * 257 + kk];
        float m0 = 0.5f * (float)(mq & 3);
        float m1 = 0.5f * (float)(mq >> 2);
        SR[ak] = m0 * X0r - m1 * X1i;
        SI[ak] = m0 * X0i + m1 * X1r;
        SR[an] = m0 * X0r + m1 * X1i;
        SI[an] = m1 * X1r - m0 * X0i;
      }
    }
  }
  __syncthreads();

  // ---- inverse DIT (bitrev in -> natural out) ----
  for (int s = 1; s <= 9; ++s){
    int half = 1 << (s - 1);
    #pragma unroll
    for (int it = 0; it < 8; ++it){
      int j  = it;
      int bi = tid;
      int pos = bi & (half - 1);
      int g = bi >> (s - 1);
      int i1 = (g << s) + pos;
      int i2 = i1 + half;
      int a1 = j * PITCH + lphys(i1);
      int a2 = j * PITCH + lphys(i2);
      float2 w = tw[pos << (9 - s)];
      float vr = SR[a2], vi = SI[a2];
      float tx_ = vr * w.x + vi * w.y;    // v * conj(w)
      float ty_ = vi * w.x - vr * w.y;
      float ur = SR[a1], ui = SI[a1];
      SR[a1] = ur + tx_; SI[a1] = ui + ty_;
      SR[a2] = ur - tx_; SI[a2] = ui - ty_;
    }
    __syncthreads();
  }

  // ---- fused augmentation + noise epilogue (packed in-place mn r/w) ----
  const float inv512 = 1.0f / 512.0f;
  u32* mnb = mn + (size_t)b * Nd;
  #pragma unroll
  for (int s = 0; s < 8; ++s){
    int qq = (s << 8) + tid;
    int t  = qq >> 2;
    int f4 = qq & 3;
    int f  = f0 + (f4 << 2);
    int j  = f4 << 1;
    int pt = lphys(t);
    int nidx = t * 64 + f;
    float4 xv = *(const float4*)(xb + nidx);
    int wi = warp_idx_(t, wpb, shb);
    float4 wv = *(const float4*)(xb + wi * 64 + f);
    float4 sc = *(const float4*)(scl + b * 64 + f);
    uint4 w4 = *(const uint4*)(mnb + nidx);
    float fr[4];
    fr[0] = SR[j * PITCH + pt] * inv512;
    fr[1] = SI[j * PITCH + pt] * inv512;
    fr[2] = SR[(j + 1) * PITCH + pt] * inv512;
    fr[3] = SI[(j + 1) * PITCH + pt] * inv512;
    const float xvv[4] = {xv.x, xv.y, xv.z, xv.w};
    const float wvv[4] = {wv.x, wv.y, wv.z, wv.w};
    const float scv[4] = {sc.x, sc.y, sc.z, sc.w};
    const u32 wdv[4] = {w4.x, w4.y, w4.z, w4.w};
    float o[4];
    #pragma unroll
    for (int c = 0; c < 4; ++c){
      float maskv = sigmoid_fast_(bf2f((u16)(wdv[c] & 0xFFFFu)));
      maskv = 1.0f - (1.0f - maskv) * s_mask * 0.3f;
      // fused noise (bit-identical R14 path incl. double bf16 rounding):
      float nm = softplus_fast_(bf2f((u16)(wdv[c] >> 16)));
      float nz = normal_fast_(rb32(knk.a, knk.b, (u32)(b * Nd + nidx + c)));
      float noise = bf2f(f2bf(nz * nm * scn));
      float fq = pass ? xvv[c] : fr[c];
      float aug = fmaf(xvv[c] * maskv, scv[c], noise);
      o[c] = aug * wa + fq * wb + wvv[c] * wc;
    }
    *(float4*)(mnb + nidx) = make_float4(o[0], o[1], o[2], o[3]);
  }
}

// ---------------------------------------------------------------------------
extern "C" void kernel_launch(void* const* d_in, const int* in_sizes, int n_in,
                              void* d_out, int out_size, void* d_ws, size_t ws_size,
                              hipStream_t stream)
{
  (void)in_sizes; (void)n_in; (void)out_size; (void)ws_size;
  const float* x   = (const float*)d_in[0];
  const float* w1  = (const float*)d_in[2];
  const float* b1  = (const float*)d_in[3];
  const float* w2  = (const float*)d_in[4];
  const float* b2  = (const float*)d_in[5];
  const float* w3  = (const float*)d_in[6];
  const float* b3  = (const float*)d_in[7];
  const float* wm  = (const float*)d_in[8];
  const float* bm  = (const float*)d_in[9];
  const float* wn  = (const float*)d_in[10];
  const float* bn  = (const float*)d_in[11];
  const float* wsc = (const float*)d_in[12];
  const float* bsc = (const float*)d_in[13];
  const float* pm  = (const float*)d_in[14];
  const float* pn  = (const float*)d_in[15];
  const float* psh = (const float*)d_in[16];
  const float* psc = (const float*)d_in[17];
  char* ws = (char*)d_ws;

  // ws: wp 1KB | shv 1KB+pad | h3b 128KB | scl 64KB | fm 2.06MB  (~2.3MB)
  int*   wp   = (int*)(ws + 0);
  int*   shv  = (int*)(ws + 1024);
  u16*   h3b  = (u16*)(ws + 4096);
  float* scl  = (float*)(ws + 4096 + 131072);
  u8*    fm   = (u8*) (ws + 4096 + 131072 + 65536);
  u32*   mn   = (u32*)d_out;

  k_mlp  <<<dim3(8192),    dim3(256), 0, stream>>>(w1, b1, w2, b2, w3, b3,
                                                   wsc, bsc, psc, psh,
                                                   h3b, scl, wp, shv, fm);
  k_gemm <<<dim3(256, 2),  dim3(256), 0, stream>>>(h3b, wm, bm, wn, bn, mn);
  k_faug <<<dim3(1024),    dim3(256), 0, stream>>>(x, mn, scl, wp, shv, fm,
                                                   pm, pn, psh);
}